// Round 1
// baseline (1863.590 us; speedup 1.0000x reference)
//
#include <hip/hip_runtime.h>

// GAT 2-layer forward, MI355X. N=100000, E=1.6M (+N self-loops), Fin=128,
// H=8, C=16 (H*C=128), Fout=64, 256 graphs.
//
// Softmax max-subtraction is dropped (mathematically identity, e is O(1)).
// Edge aggregation: atomic scatter of exp(e)*xl[src] into out[dst].

#define LRELU_SLOPE 0.2f

__device__ __forceinline__ float lrelu(float x) { return x > 0.f ? x : LRELU_SLOPE * x; }

// ---------------- GEMM: Y[N][M_] = X[N][128] @ W[128][M_], f32 vector ALU ----
template<int M_, int BM, int KB>
__global__ __launch_bounds__(256) void gemm_rm(const float* __restrict__ X,
    const float* __restrict__ W, float* __restrict__ Y, int N) {
  constexpr int K = 128;
  constexpr int NTX = M_ / 4;        // col-groups of 4
  constexpr int NTY = 256 / NTX;
  constexpr int RT  = BM / NTY;      // rows per thread
  __shared__ float Wl[KB * M_];
  __shared__ float Xl[BM * (K + 1)]; // +1 pad: conflict-free column reads
  const int tid  = threadIdx.x;
  const int row0 = blockIdx.x * BM;

  // stage X tile once (float4 loads, scalar LDS stores due to pad)
  for (int i = tid; i < BM * (K / 4); i += 256) {
    const int r = i / (K / 4), c4 = i % (K / 4);
    int gr = row0 + r; if (gr >= N) gr = N - 1;
    const float4 v = ((const float4*)(X + (size_t)gr * K))[c4];
    float* d = &Xl[r * (K + 1) + c4 * 4];
    d[0] = v.x; d[1] = v.y; d[2] = v.z; d[3] = v.w;
  }
  const int tx = tid % NTX, ty = tid / NTX;
  float4 acc[RT];
#pragma unroll
  for (int i = 0; i < RT; ++i) acc[i] = make_float4(0.f, 0.f, 0.f, 0.f);

  for (int kb = 0; kb < K; kb += KB) {
    __syncthreads();   // protects Xl (first iter) and previous Wl reads
    for (int i = tid; i < KB * M_ / 4; i += 256)
      ((float4*)Wl)[i] = ((const float4*)(W + (size_t)kb * M_))[i];
    __syncthreads();
#pragma unroll 8
    for (int k = 0; k < KB; ++k) {
      const float4 w = *(const float4*)&Wl[k * M_ + tx * 4];
#pragma unroll
      for (int i = 0; i < RT; ++i) {
        const float xv = Xl[(ty * RT + i) * (K + 1) + kb + k];
        acc[i].x += xv * w.x; acc[i].y += xv * w.y;
        acc[i].z += xv * w.z; acc[i].w += xv * w.w;
      }
    }
  }
#pragma unroll
  for (int i = 0; i < RT; ++i) {
    const int gr = row0 + ty * RT + i;
    if (gr < N) ((float4*)(Y + (size_t)gr * M_))[tx] = acc[i];
  }
}

// ---------------- attention scalars: es/ed[n,h] = sum_c xl[n,h,c]*a[h,c] -----
__global__ __launch_bounds__(256) void att_h8(const float* __restrict__ xl,
    const float* __restrict__ as, const float* __restrict__ ad,
    float* __restrict__ es, float* __restrict__ ed, int N) {
  const int n = blockIdx.x * 2 + (threadIdx.x >> 7);
  const int c = threadIdx.x & 127;
  if (n >= N) return;
  const float v = xl[(size_t)n * 128 + c];
  float ps = v * as[c];
  float pd = v * ad[c];
#pragma unroll
  for (int o = 8; o >= 1; o >>= 1) {
    ps += __shfl_xor(ps, o, 16);
    pd += __shfl_xor(pd, o, 16);
  }
  if ((c & 15) == 0) {
    es[n * 8 + (c >> 4)] = ps;
    ed[n * 8 + (c >> 4)] = pd;
  }
}

__global__ __launch_bounds__(256) void att_h1(const float* __restrict__ xl2,
    const float* __restrict__ as, const float* __restrict__ ad,
    float* __restrict__ es, float* __restrict__ ed, int N) {
  const int n = blockIdx.x * 4 + (threadIdx.x >> 6);
  const int c = threadIdx.x & 63;
  if (n >= N) return;
  const float v = xl2[(size_t)n * 64 + c];
  float ps = v * as[c];
  float pd = v * ad[c];
#pragma unroll
  for (int o = 32; o >= 1; o >>= 1) {
    ps += __shfl_xor(ps, o, 64);
    pd += __shfl_xor(pd, o, 64);
  }
  if (c == 0) { es[n] = ps; ed[n] = pd; }
}

// ---------------- self-loop init (also zero-init of accumulators) -----------
__global__ __launch_bounds__(256) void selfinit_h8(const float* __restrict__ xl,
    const float* __restrict__ es, const float* __restrict__ ed,
    float* __restrict__ out, float* __restrict__ s, int N) {
  const int n = blockIdx.x * 2 + (threadIdx.x >> 7);
  const int c = threadIdx.x & 127;
  if (n >= N) return;
  const int h = c >> 4;
  const float ee = __expf(lrelu(es[n * 8 + h] + ed[n * 8 + h]));
  out[(size_t)n * 128 + c] = ee * xl[(size_t)n * 128 + c];
  if ((c & 15) == 0) s[n * 8 + h] = ee;
}

__global__ __launch_bounds__(256) void selfinit_h1(const float* __restrict__ xl2,
    const float* __restrict__ es, const float* __restrict__ ed,
    float* __restrict__ out, float* __restrict__ s, int N) {
  const int n = blockIdx.x * 4 + (threadIdx.x >> 6);
  const int c = threadIdx.x & 63;
  if (n >= N) return;
  const float ee = __expf(lrelu(es[n] + ed[n]));
  out[(size_t)n * 64 + c] = ee * xl2[(size_t)n * 64 + c];
  if (c == 0) s[n] = ee;
}

// ---------------- edge scatter ----------------------------------------------
__global__ __launch_bounds__(256) void edge_h8(const int* __restrict__ ei, int E,
    const float* __restrict__ xl, const float* __restrict__ es,
    const float* __restrict__ ed, float* __restrict__ out, float* __restrict__ s) {
  const int e = blockIdx.x * 2 + (threadIdx.x >> 7);
  if (e >= E) return;
  const int c = threadIdx.x & 127;
  const int src = ei[e];
  const int dst = ei[E + e];
  const int h = c >> 4;
  const float ee = __expf(lrelu(es[src * 8 + h] + ed[dst * 8 + h]));
  atomicAdd(&out[(size_t)dst * 128 + c], ee * xl[(size_t)src * 128 + c]);
  if ((c & 15) == 0) atomicAdd(&s[dst * 8 + h], ee);
}

__global__ __launch_bounds__(256) void edge_h1(const int* __restrict__ ei, int E,
    const float* __restrict__ xl2, const float* __restrict__ es,
    const float* __restrict__ ed, float* __restrict__ out, float* __restrict__ s) {
  const int e = blockIdx.x * 4 + (threadIdx.x >> 6);
  if (e >= E) return;
  const int c = threadIdx.x & 63;
  const int src = ei[e];
  const int dst = ei[E + e];
  const float ee = __expf(lrelu(es[src] + ed[dst]));
  atomicAdd(&out[(size_t)dst * 64 + c], ee * xl2[(size_t)src * 64 + c]);
  if (c == 0) atomicAdd(&s[dst], ee);
}

// ---------------- finalize layer 1: h = elu(out/s + bias) -------------------
__global__ __launch_bounds__(256) void fin1(const float* __restrict__ out1,
    const float* __restrict__ s1, const float* __restrict__ bias,
    float* __restrict__ h, int NC) {
  const int i = blockIdx.x * 256 + threadIdx.x;
  if (i >= NC) return;
  const int n = i >> 7, c = i & 127;
  const float v = out1[i] / (s1[n * 8 + (c >> 4)] + 1e-16f) + bias[c];
  h[i] = v > 0.f ? v : __expf(v) - 1.f;
}

// ---------------- zero pool accumulators ------------------------------------
__global__ __launch_bounds__(256) void zeropool(float* __restrict__ pool, int n) {
  const int i = blockIdx.x * 256 + threadIdx.x;
  if (i < n) pool[i] = 0.f;
}

// ---------------- finalize layer 2 + global mean pool (atomics) -------------
__global__ __launch_bounds__(256) void fin2pool(const float* __restrict__ out2,
    const float* __restrict__ s2, const float* __restrict__ bias,
    const int* __restrict__ batch, float* __restrict__ pool,
    float* __restrict__ cnt, int N) {
  const int n = blockIdx.x * 4 + (threadIdx.x >> 6);
  const int c = threadIdx.x & 63;
  if (n >= N) return;
  const float v = out2[(size_t)n * 64 + c] / (s2[n] + 1e-16f) + bias[c];
  const int g = batch[n];
  atomicAdd(&pool[g * 64 + c], v);
  if (c == 0) atomicAdd(&cnt[g], 1.f);
}

__global__ __launch_bounds__(256) void finalout(const float* __restrict__ pool,
    const float* __restrict__ cnt, float* __restrict__ out, int n) {
  const int i = blockIdx.x * 256 + threadIdx.x;
  if (i < n) out[i] = pool[i] / fmaxf(cnt[i >> 6], 1.f);
}

extern "C" void kernel_launch(void* const* d_in, const int* in_sizes, int n_in,
                              void* d_out, int out_size, void* d_ws, size_t ws_size,
                              hipStream_t stream) {
  const float* x   = (const float*)d_in[0];
  const float* W1  = (const float*)d_in[1];
  const float* as1 = (const float*)d_in[2];
  const float* ad1 = (const float*)d_in[3];
  const float* b1  = (const float*)d_in[4];
  const float* W2  = (const float*)d_in[5];
  const float* as2 = (const float*)d_in[6];
  const float* ad2 = (const float*)d_in[7];
  const float* b2  = (const float*)d_in[8];
  const int* ei    = (const int*)d_in[9];
  const int* batch = (const int*)d_in[10];
  float* out = (float*)d_out;
  const int N = in_sizes[10];      // 100000
  const int E = in_sizes[9] / 2;   // 1600000

  // workspace layout (floats), with reuse:
  float* ws   = (float*)d_ws;
  float* xl   = ws;                         // [N*128] layer1 proj; reused as h
  float* out1 = ws + (size_t)N * 128;       // [N*128] layer1 accum
  float* xl2  = out1;                       // [N*64]  layer2 proj (out1 dead)
  float* out2 = out1 + (size_t)N * 64;      // [N*64]  layer2 accum
  float* es1  = ws + (size_t)N * 256;       // [N*8]
  float* ed1  = es1 + (size_t)N * 8;        // [N*8]
  float* s1   = ed1 + (size_t)N * 8;        // [N*8]
  float* pool = s1 + (size_t)N * 8;         // [256*64]
  float* cnt  = pool + 16384;               // [256]
  float* es2 = es1; float* ed2 = ed1; float* s2 = s1;  // layer2 reuse
  float* h = xl;

  // ---- layer 1 ----
  gemm_rm<128, 32, 64><<<(N + 31) / 32, 256, 0, stream>>>(x, W1, xl, N);
  att_h8<<<(N + 1) / 2, 256, 0, stream>>>(xl, as1, ad1, es1, ed1, N);
  selfinit_h8<<<(N + 1) / 2, 256, 0, stream>>>(xl, es1, ed1, out1, s1, N);
  edge_h8<<<(E + 1) / 2, 256, 0, stream>>>(ei, E, xl, es1, ed1, out1, s1);
  fin1<<<(N * 128 + 255) / 256, 256, 0, stream>>>(out1, s1, b1, h, N * 128);

  // ---- layer 2 ----
  gemm_rm<64, 64, 128><<<(N + 63) / 64, 256, 0, stream>>>(h, W2, xl2, N);
  att_h1<<<(N + 3) / 4, 256, 0, stream>>>(xl2, as2, ad2, es2, ed2, N);
  selfinit_h1<<<(N + 3) / 4, 256, 0, stream>>>(xl2, es2, ed2, out2, s2, N);
  edge_h1<<<(E + 3) / 4, 256, 0, stream>>>(ei, E, xl2, es2, ed2, out2, s2);

  // ---- global mean pool ----
  zeropool<<<(16384 + 256 + 255) / 256, 256, 0, stream>>>(pool, 16384 + 256);
  fin2pool<<<(N + 3) / 4, 256, 0, stream>>>(out2, s2, b2, batch, pool, cnt, N);
  finalout<<<64, 256, 0, stream>>>(pool, cnt, out, 16384);
}

// Round 2
// 1028.235 us; speedup vs baseline: 1.8124x; 1.8124x over previous
//
#include <hip/hip_runtime.h>

// GAT 2-layer forward, MI355X. N=100000, E=1.6M (+N self-loops), Fin=128,
// H=8, C=16 (H*C=128), Fout=64, 256 graphs.
//
// Round 2: replace atomic edge-scatter with dst-CSR gather (built on device
// each call). One wave per dst node accumulates in registers; fuses
// self-loop, softmax-normalize, bias, ELU (layer 1) and pooling (layer 2).

#define LRELU_SLOPE 0.2f

__device__ __forceinline__ float lrelu(float x) { return x > 0.f ? x : LRELU_SLOPE * x; }

// ---------------- GEMM: Y[N][M_] = X[N][128] @ W[128][M_], f32 vector ALU ----
template<int M_, int BM, int KB>
__global__ __launch_bounds__(256) void gemm_rm(const float* __restrict__ X,
    const float* __restrict__ W, float* __restrict__ Y, int N) {
  constexpr int K = 128;
  constexpr int NTX = M_ / 4;        // col-groups of 4
  constexpr int NTY = 256 / NTX;
  constexpr int RT  = BM / NTY;      // rows per thread
  __shared__ float Wl[KB * M_];
  __shared__ float Xl[BM * (K + 1)];
  const int tid  = threadIdx.x;
  const int row0 = blockIdx.x * BM;

  for (int i = tid; i < BM * (K / 4); i += 256) {
    const int r = i / (K / 4), c4 = i % (K / 4);
    int gr = row0 + r; if (gr >= N) gr = N - 1;
    const float4 v = ((const float4*)(X + (size_t)gr * K))[c4];
    float* d = &Xl[r * (K + 1) + c4 * 4];
    d[0] = v.x; d[1] = v.y; d[2] = v.z; d[3] = v.w;
  }
  const int tx = tid % NTX, ty = tid / NTX;
  float4 acc[RT];
#pragma unroll
  for (int i = 0; i < RT; ++i) acc[i] = make_float4(0.f, 0.f, 0.f, 0.f);

  for (int kb = 0; kb < K; kb += KB) {
    __syncthreads();
    for (int i = tid; i < KB * M_ / 4; i += 256)
      ((float4*)Wl)[i] = ((const float4*)(W + (size_t)kb * M_))[i];
    __syncthreads();
#pragma unroll 8
    for (int k = 0; k < KB; ++k) {
      const float4 w = *(const float4*)&Wl[k * M_ + tx * 4];
#pragma unroll
      for (int i = 0; i < RT; ++i) {
        const float xv = Xl[(ty * RT + i) * (K + 1) + kb + k];
        acc[i].x += xv * w.x; acc[i].y += xv * w.y;
        acc[i].z += xv * w.z; acc[i].w += xv * w.w;
      }
    }
  }
#pragma unroll
  for (int i = 0; i < RT; ++i) {
    const int gr = row0 + ty * RT + i;
    if (gr < N) ((float4*)(Y + (size_t)gr * M_))[tx] = acc[i];
  }
}

// ---------------- attention scalars ----------------------------------------
__global__ __launch_bounds__(256) void att_h8(const float* __restrict__ xl,
    const float* __restrict__ as, const float* __restrict__ ad,
    float* __restrict__ es, float* __restrict__ ed, int N) {
  const int n = blockIdx.x * 2 + (threadIdx.x >> 7);
  const int c = threadIdx.x & 127;
  if (n >= N) return;
  const float v = xl[(size_t)n * 128 + c];
  float ps = v * as[c];
  float pd = v * ad[c];
#pragma unroll
  for (int o = 8; o >= 1; o >>= 1) {
    ps += __shfl_xor(ps, o, 16);
    pd += __shfl_xor(pd, o, 16);
  }
  if ((c & 15) == 0) {
    es[n * 8 + (c >> 4)] = ps;
    ed[n * 8 + (c >> 4)] = pd;
  }
}

__global__ __launch_bounds__(256) void att_h1(const float* __restrict__ xl2,
    const float* __restrict__ as, const float* __restrict__ ad,
    float* __restrict__ es, float* __restrict__ ed, int N) {
  const int n = blockIdx.x * 4 + (threadIdx.x >> 6);
  const int c = threadIdx.x & 63;
  if (n >= N) return;
  const float v = xl2[(size_t)n * 64 + c];
  float ps = v * as[c];
  float pd = v * ad[c];
#pragma unroll
  for (int o = 32; o >= 1; o >>= 1) {
    ps += __shfl_xor(ps, o, 64);
    pd += __shfl_xor(pd, o, 64);
  }
  if (c == 0) { es[n] = ps; ed[n] = pd; }
}

// ---------------- CSR build --------------------------------------------------
__global__ __launch_bounds__(256) void zero_int(int* __restrict__ p, int n) {
  const int i = blockIdx.x * 256 + threadIdx.x;
  if (i < n) p[i] = 0;
}

__global__ __launch_bounds__(256) void count_deg(const int* __restrict__ ei, int E,
    int* __restrict__ deg) {
  const int e = blockIdx.x * 256 + threadIdx.x;
  if (e < E) atomicAdd(&deg[ei[E + e]], 1);
}

// in-place block-local exclusive scan over chunks of 1024 (each thread owns 4)
__global__ __launch_bounds__(256) void scanA(int* __restrict__ a, int* __restrict__ ctot, int N) {
  __shared__ int sm[256];
  const int base = blockIdx.x * 1024;
  const int t = threadIdx.x;
  int v[4], s = 0;
#pragma unroll
  for (int i = 0; i < 4; ++i) {
    const int idx = base + t * 4 + i;
    v[i] = (idx < N) ? a[idx] : 0;
    s += v[i];
  }
  sm[t] = s;
  __syncthreads();
  for (int o = 1; o < 256; o <<= 1) {
    const int x = (t >= o) ? sm[t - o] : 0;
    __syncthreads();
    sm[t] += x;
    __syncthreads();
  }
  if (t == 255) ctot[blockIdx.x] = sm[255];
  int run = sm[t] - s;   // exclusive prefix of this thread's 4-group
#pragma unroll
  for (int i = 0; i < 4; ++i) {
    const int idx = base + t * 4 + i;
    if (idx < N) a[idx] = run;
    run += v[i];
  }
}

__global__ __launch_bounds__(128) void scanB(int* __restrict__ ctot, int n) {
  __shared__ int sm[128];
  const int t = threadIdx.x;
  const int v = (t < n) ? ctot[t] : 0;
  sm[t] = v;
  __syncthreads();
  for (int o = 1; o < 128; o <<= 1) {
    const int x = (t >= o) ? sm[t - o] : 0;
    __syncthreads();
    sm[t] += x;
    __syncthreads();
  }
  if (t < n) ctot[t] = sm[t] - v;   // exclusive
}

__global__ __launch_bounds__(256) void scanC(int* __restrict__ a, const int* __restrict__ ctot, int N) {
  const int i = blockIdx.x * 256 + threadIdx.x;
  if (i < N) a[i] += ctot[i >> 10];
}

// fill: mutates rowptr so that post-fill rowptr[n] == original rowptr[n+1]
// (end of node n); start of node n is (n==0)?0:rowptr[n-1].
__global__ __launch_bounds__(256) void fill_csr(const int* __restrict__ ei, int E,
    int* __restrict__ rowptr, int* __restrict__ csr) {
  const int e = blockIdx.x * 256 + threadIdx.x;
  if (e < E) {
    const int slot = atomicAdd(&rowptr[ei[E + e]], 1);
    csr[slot] = ei[e];
  }
}

// ---------------- layer-1 gather: one wave per dst node ---------------------
// lane handles channels 2l,2l+1 (head = l>>3). Fuses self-loop, normalize,
// bias, ELU. Writes h directly.
__global__ __launch_bounds__(256) void gather_h8(const float* __restrict__ xl,
    const float* __restrict__ es, const float* __restrict__ ed,
    const int* __restrict__ rowptr, const int* __restrict__ csr,
    const float* __restrict__ bias, float* __restrict__ hout, int N) {
  const int wave = threadIdx.x >> 6, lane = threadIdx.x & 63;
  const int n = blockIdx.x * 4 + wave;
  if (n >= N) return;
  const int h = lane >> 3;
  const float edv = ed[n * 8 + h];
  const int start = (n == 0) ? 0 : rowptr[n - 1];
  const int end = rowptr[n];

  float2 acc;
  float ssum;
  {  // self loop
    const float ee = __expf(lrelu(es[n * 8 + h] + edv));
    const float2 xv = *(const float2*)&xl[(size_t)n * 128 + lane * 2];
    acc.x = ee * xv.x; acc.y = ee * xv.y; ssum = ee;
  }
  for (int j = start; j < end; ++j) {
    const int src = csr[j];
    const float ee = __expf(lrelu(es[src * 8 + h] + edv));
    const float2 xv = *(const float2*)&xl[(size_t)src * 128 + lane * 2];
    acc.x += ee * xv.x; acc.y += ee * xv.y; ssum += ee;
  }
  const float inv = 1.f / (ssum + 1e-16f);
  const int c = lane * 2;
  float v0 = acc.x * inv + bias[c];
  float v1 = acc.y * inv + bias[c + 1];
  v0 = v0 > 0.f ? v0 : __expf(v0) - 1.f;
  v1 = v1 > 0.f ? v1 : __expf(v1) - 1.f;
  *(float2*)&hout[(size_t)n * 128 + c] = make_float2(v0, v1);
}

// ---------------- layer-2 gather + global mean pool -------------------------
__global__ __launch_bounds__(256) void gather_h1_pool(const float* __restrict__ xl2,
    const float* __restrict__ es, const float* __restrict__ ed,
    const int* __restrict__ rowptr, const int* __restrict__ csr,
    const float* __restrict__ bias, const int* __restrict__ batch,
    float* __restrict__ pool, float* __restrict__ cnt, int N) {
  const int wave = threadIdx.x >> 6, lane = threadIdx.x & 63;
  const int n = blockIdx.x * 4 + wave;
  if (n >= N) return;
  const float edv = ed[n];
  const int start = (n == 0) ? 0 : rowptr[n - 1];
  const int end = rowptr[n];

  float ee = __expf(lrelu(es[n] + edv));           // self loop
  float acc = ee * xl2[(size_t)n * 64 + lane];
  float ssum = ee;
  for (int j = start; j < end; ++j) {
    const int src = csr[j];
    const float e2 = __expf(lrelu(es[src] + edv));
    acc += e2 * xl2[(size_t)src * 64 + lane];
    ssum += e2;
  }
  const float v = acc / (ssum + 1e-16f) + bias[lane];
  const int g = batch[n];
  atomicAdd(&pool[g * 64 + lane], v);
  if (lane == 0) atomicAdd(&cnt[g], 1.f);
}

__global__ __launch_bounds__(256) void zeropool(float* __restrict__ pool, int n) {
  const int i = blockIdx.x * 256 + threadIdx.x;
  if (i < n) pool[i] = 0.f;
}

__global__ __launch_bounds__(256) void finalout(const float* __restrict__ pool,
    const float* __restrict__ cnt, float* __restrict__ out, int n) {
  const int i = blockIdx.x * 256 + threadIdx.x;
  if (i < n) out[i] = pool[i] / fmaxf(cnt[i >> 6], 1.f);
}

extern "C" void kernel_launch(void* const* d_in, const int* in_sizes, int n_in,
                              void* d_out, int out_size, void* d_ws, size_t ws_size,
                              hipStream_t stream) {
  const float* x   = (const float*)d_in[0];
  const float* W1  = (const float*)d_in[1];
  const float* as1 = (const float*)d_in[2];
  const float* ad1 = (const float*)d_in[3];
  const float* b1  = (const float*)d_in[4];
  const float* W2  = (const float*)d_in[5];
  const float* as2 = (const float*)d_in[6];
  const float* ad2 = (const float*)d_in[7];
  const float* b2  = (const float*)d_in[8];
  const int* ei    = (const int*)d_in[9];
  const int* batch = (const int*)d_in[10];
  float* out = (float*)d_out;
  const int N = in_sizes[10];      // 100000
  const int E = in_sizes[9] / 2;   // 1600000
  const int NCHUNK = (N + 1023) / 1024;

  // workspace layout (floats), with reuse:
  float* ws   = (float*)d_ws;
  float* xl   = ws;                         // [N*128] layer1 proj
  float* h    = ws + (size_t)N * 128;       // [N*128] layer1 output
  float* xl2  = xl;                         // [N*64]  layer2 proj (xl dead)
  float* es1  = ws + (size_t)N * 256;       // [N*8]
  float* ed1  = es1 + (size_t)N * 8;        // [N*8]
  float* es2  = es1;                        // [N] (es1 dead after gather_h8)
  float* ed2  = es1 + N;                    // [N]
  float* pool = ws + (size_t)N * 272;       // [256*64]
  float* cnt  = pool + 16384;               // [256]
  int* rowptr = (int*)(cnt + 256);          // [N]
  int* csr    = rowptr + N;                 // [E]
  int* ctot   = csr + E;                    // [NCHUNK]

  // ---- CSR build (dst-grouped) ----
  zero_int<<<(N + 255) / 256, 256, 0, stream>>>(rowptr, N);
  count_deg<<<(E + 255) / 256, 256, 0, stream>>>(ei, E, rowptr);
  scanA<<<NCHUNK, 256, 0, stream>>>(rowptr, ctot, N);
  scanB<<<1, 128, 0, stream>>>(ctot, NCHUNK);
  scanC<<<(N + 255) / 256, 256, 0, stream>>>(rowptr, ctot, N);
  fill_csr<<<(E + 255) / 256, 256, 0, stream>>>(ei, E, rowptr, csr);

  // ---- layer 1 ----
  gemm_rm<128, 32, 64><<<(N + 31) / 32, 256, 0, stream>>>(x, W1, xl, N);
  att_h8<<<(N + 1) / 2, 256, 0, stream>>>(xl, as1, ad1, es1, ed1, N);
  gather_h8<<<(N + 3) / 4, 256, 0, stream>>>(xl, es1, ed1, rowptr, csr, b1, h, N);

  // ---- layer 2 ----
  gemm_rm<64, 64, 128><<<(N + 63) / 64, 256, 0, stream>>>(h, W2, xl2, N);
  att_h1<<<(N + 3) / 4, 256, 0, stream>>>(xl2, as2, ad2, es2, ed2, N);
  zeropool<<<(16384 + 256 + 255) / 256, 256, 0, stream>>>(pool, 16384 + 256);
  gather_h1_pool<<<(N + 3) / 4, 256, 0, stream>>>(xl2, es2, ed2, rowptr, csr, b2,
                                                  batch, pool, cnt, N);

  // ---- output ----
  finalout<<<64, 256, 0, stream>>>(pool, cnt, out, 16384);
}

// Round 3
// 971.126 us; speedup vs baseline: 1.9190x; 1.0588x over previous
//
#include <hip/hip_runtime.h>

// GAT 2-layer forward, MI355X. N=100000, E=1.6M (+N self-loops), Fin=128,
// H=8, C=16 (H*C=128), Fout=64, 256 graphs.
//
// Round 3: software-prefetched (P=8) CSR gathers — 8 independent row loads
// in flight per wave instead of a serial dependent chain.

#define LRELU_SLOPE 0.2f

__device__ __forceinline__ float lrelu(float x) { return x > 0.f ? x : LRELU_SLOPE * x; }

// ---------------- GEMM: Y[N][M_] = X[N][128] @ W[128][M_], f32 vector ALU ----
template<int M_, int BM, int KB>
__global__ __launch_bounds__(256) void gemm_rm(const float* __restrict__ X,
    const float* __restrict__ W, float* __restrict__ Y, int N) {
  constexpr int K = 128;
  constexpr int NTX = M_ / 4;        // col-groups of 4
  constexpr int NTY = 256 / NTX;
  constexpr int RT  = BM / NTY;      // rows per thread
  __shared__ float Wl[KB * M_];
  __shared__ float Xl[BM * (K + 1)];
  const int tid  = threadIdx.x;
  const int row0 = blockIdx.x * BM;

  for (int i = tid; i < BM * (K / 4); i += 256) {
    const int r = i / (K / 4), c4 = i % (K / 4);
    int gr = row0 + r; if (gr >= N) gr = N - 1;
    const float4 v = ((const float4*)(X + (size_t)gr * K))[c4];
    float* d = &Xl[r * (K + 1) + c4 * 4];
    d[0] = v.x; d[1] = v.y; d[2] = v.z; d[3] = v.w;
  }
  const int tx = tid % NTX, ty = tid / NTX;
  float4 acc[RT];
#pragma unroll
  for (int i = 0; i < RT; ++i) acc[i] = make_float4(0.f, 0.f, 0.f, 0.f);

  for (int kb = 0; kb < K; kb += KB) {
    __syncthreads();
    for (int i = tid; i < KB * M_ / 4; i += 256)
      ((float4*)Wl)[i] = ((const float4*)(W + (size_t)kb * M_))[i];
    __syncthreads();
#pragma unroll 8
    for (int k = 0; k < KB; ++k) {
      const float4 w = *(const float4*)&Wl[k * M_ + tx * 4];
#pragma unroll
      for (int i = 0; i < RT; ++i) {
        const float xv = Xl[(ty * RT + i) * (K + 1) + kb + k];
        acc[i].x += xv * w.x; acc[i].y += xv * w.y;
        acc[i].z += xv * w.z; acc[i].w += xv * w.w;
      }
    }
  }
#pragma unroll
  for (int i = 0; i < RT; ++i) {
    const int gr = row0 + ty * RT + i;
    if (gr < N) ((float4*)(Y + (size_t)gr * M_))[tx] = acc[i];
  }
}

// ---------------- attention scalars ----------------------------------------
__global__ __launch_bounds__(256) void att_h8(const float* __restrict__ xl,
    const float* __restrict__ as, const float* __restrict__ ad,
    float* __restrict__ es, float* __restrict__ ed, int N) {
  const int n = blockIdx.x * 2 + (threadIdx.x >> 7);
  const int c = threadIdx.x & 127;
  if (n >= N) return;
  const float v = xl[(size_t)n * 128 + c];
  float ps = v * as[c];
  float pd = v * ad[c];
#pragma unroll
  for (int o = 8; o >= 1; o >>= 1) {
    ps += __shfl_xor(ps, o, 16);
    pd += __shfl_xor(pd, o, 16);
  }
  if ((c & 15) == 0) {
    es[n * 8 + (c >> 4)] = ps;
    ed[n * 8 + (c >> 4)] = pd;
  }
}

__global__ __launch_bounds__(256) void att_h1(const float* __restrict__ xl2,
    const float* __restrict__ as, const float* __restrict__ ad,
    float* __restrict__ es, float* __restrict__ ed, int N) {
  const int n = blockIdx.x * 4 + (threadIdx.x >> 6);
  const int c = threadIdx.x & 63;
  if (n >= N) return;
  const float v = xl2[(size_t)n * 64 + c];
  float ps = v * as[c];
  float pd = v * ad[c];
#pragma unroll
  for (int o = 32; o >= 1; o >>= 1) {
    ps += __shfl_xor(ps, o, 64);
    pd += __shfl_xor(pd, o, 64);
  }
  if (c == 0) { es[n] = ps; ed[n] = pd; }
}

// ---------------- CSR build --------------------------------------------------
__global__ __launch_bounds__(256) void zero_int(int* __restrict__ p, int n) {
  const int i = blockIdx.x * 256 + threadIdx.x;
  if (i < n) p[i] = 0;
}

__global__ __launch_bounds__(256) void count_deg(const int* __restrict__ ei, int E,
    int* __restrict__ deg) {
  const int e = blockIdx.x * 256 + threadIdx.x;
  if (e < E) atomicAdd(&deg[ei[E + e]], 1);
}

__global__ __launch_bounds__(256) void scanA(int* __restrict__ a, int* __restrict__ ctot, int N) {
  __shared__ int sm[256];
  const int base = blockIdx.x * 1024;
  const int t = threadIdx.x;
  int v[4], s = 0;
#pragma unroll
  for (int i = 0; i < 4; ++i) {
    const int idx = base + t * 4 + i;
    v[i] = (idx < N) ? a[idx] : 0;
    s += v[i];
  }
  sm[t] = s;
  __syncthreads();
  for (int o = 1; o < 256; o <<= 1) {
    const int x = (t >= o) ? sm[t - o] : 0;
    __syncthreads();
    sm[t] += x;
    __syncthreads();
  }
  if (t == 255) ctot[blockIdx.x] = sm[255];
  int run = sm[t] - s;
#pragma unroll
  for (int i = 0; i < 4; ++i) {
    const int idx = base + t * 4 + i;
    if (idx < N) a[idx] = run;
    run += v[i];
  }
}

__global__ __launch_bounds__(128) void scanB(int* __restrict__ ctot, int n) {
  __shared__ int sm[128];
  const int t = threadIdx.x;
  const int v = (t < n) ? ctot[t] : 0;
  sm[t] = v;
  __syncthreads();
  for (int o = 1; o < 128; o <<= 1) {
    const int x = (t >= o) ? sm[t - o] : 0;
    __syncthreads();
    sm[t] += x;
    __syncthreads();
  }
  if (t < n) ctot[t] = sm[t] - v;
}

__global__ __launch_bounds__(256) void scanC(int* __restrict__ a, const int* __restrict__ ctot, int N) {
  const int i = blockIdx.x * 256 + threadIdx.x;
  if (i < N) a[i] += ctot[i >> 10];
}

// post-fill: rowptr[n] == end of node n; start = (n==0)?0:rowptr[n-1]
__global__ __launch_bounds__(256) void fill_csr(const int* __restrict__ ei, int E,
    int* __restrict__ rowptr, int* __restrict__ csr) {
  const int e = blockIdx.x * 256 + threadIdx.x;
  if (e < E) {
    const int slot = atomicAdd(&rowptr[ei[E + e]], 1);
    csr[slot] = ei[e];
  }
}

// ---------------- layer-1 gather (prefetched): one wave per dst node --------
__global__ __launch_bounds__(256) void gather_h8(const float* __restrict__ xl,
    const float* __restrict__ es, const float* __restrict__ ed,
    const int* __restrict__ rowptr, const int* __restrict__ csr,
    const float* __restrict__ bias, float* __restrict__ hout, int N) {
  const int wave = threadIdx.x >> 6, lane = threadIdx.x & 63;
  const int n = blockIdx.x * 4 + wave;
  if (n >= N) return;
  const int h = lane >> 3;
  const float edv = ed[n * 8 + h];
  const int start = (n == 0) ? 0 : rowptr[n - 1];
  const int end = rowptr[n];

  float2 acc;
  float ssum;
  {  // self loop
    const float ee = __expf(lrelu(es[n * 8 + h] + edv));
    const float2 xv = *(const float2*)&xl[(size_t)n * 128 + lane * 2];
    acc.x = ee * xv.x; acc.y = ee * xv.y; ssum = ee;
  }
  constexpr int P = 8;
  int j = start;
  for (; j + P <= end; j += P) {
    int srcs[P];
#pragma unroll
    for (int k = 0; k < P; ++k) srcs[k] = csr[j + k];
    float ev[P];
    float2 xv[P];
#pragma unroll
    for (int k = 0; k < P; ++k) {
      ev[k] = es[srcs[k] * 8 + h];
      xv[k] = *(const float2*)&xl[(size_t)srcs[k] * 128 + lane * 2];
    }
#pragma unroll
    for (int k = 0; k < P; ++k) {
      const float ee = __expf(lrelu(ev[k] + edv));
      acc.x += ee * xv[k].x; acc.y += ee * xv[k].y; ssum += ee;
    }
  }
  for (; j < end; ++j) {
    const int src = csr[j];
    const float ee = __expf(lrelu(es[src * 8 + h] + edv));
    const float2 xv = *(const float2*)&xl[(size_t)src * 128 + lane * 2];
    acc.x += ee * xv.x; acc.y += ee * xv.y; ssum += ee;
  }
  const float inv = 1.f / (ssum + 1e-16f);
  const int c = lane * 2;
  float v0 = acc.x * inv + bias[c];
  float v1 = acc.y * inv + bias[c + 1];
  v0 = v0 > 0.f ? v0 : __expf(v0) - 1.f;
  v1 = v1 > 0.f ? v1 : __expf(v1) - 1.f;
  *(float2*)&hout[(size_t)n * 128 + c] = make_float2(v0, v1);
}

// ---------------- layer-2 gather (prefetched) + global mean pool ------------
__global__ __launch_bounds__(256) void gather_h1_pool(const float* __restrict__ xl2,
    const float* __restrict__ es, const float* __restrict__ ed,
    const int* __restrict__ rowptr, const int* __restrict__ csr,
    const float* __restrict__ bias, const int* __restrict__ batch,
    float* __restrict__ pool, float* __restrict__ cnt, int N) {
  const int wave = threadIdx.x >> 6, lane = threadIdx.x & 63;
  const int n = blockIdx.x * 4 + wave;
  if (n >= N) return;
  const float edv = ed[n];
  const int start = (n == 0) ? 0 : rowptr[n - 1];
  const int end = rowptr[n];

  float ee0 = __expf(lrelu(es[n] + edv));          // self loop
  float acc = ee0 * xl2[(size_t)n * 64 + lane];
  float ssum = ee0;
  constexpr int P = 8;
  int j = start;
  for (; j + P <= end; j += P) {
    int srcs[P];
#pragma unroll
    for (int k = 0; k < P; ++k) srcs[k] = csr[j + k];
    float ev[P], xv[P];
#pragma unroll
    for (int k = 0; k < P; ++k) {
      ev[k] = es[srcs[k]];
      xv[k] = xl2[(size_t)srcs[k] * 64 + lane];
    }
#pragma unroll
    for (int k = 0; k < P; ++k) {
      const float e2 = __expf(lrelu(ev[k] + edv));
      acc += e2 * xv[k]; ssum += e2;
    }
  }
  for (; j < end; ++j) {
    const int src = csr[j];
    const float e2 = __expf(lrelu(es[src] + edv));
    acc += e2 * xl2[(size_t)src * 64 + lane];
    ssum += e2;
  }
  const float v = acc / (ssum + 1e-16f) + bias[lane];
  const int g = batch[n];
  atomicAdd(&pool[g * 64 + lane], v);
  if (lane == 0) atomicAdd(&cnt[g], 1.f);
}

__global__ __launch_bounds__(256) void zeropool(float* __restrict__ pool, int n) {
  const int i = blockIdx.x * 256 + threadIdx.x;
  if (i < n) pool[i] = 0.f;
}

__global__ __launch_bounds__(256) void finalout(const float* __restrict__ pool,
    const float* __restrict__ cnt, float* __restrict__ out, int n) {
  const int i = blockIdx.x * 256 + threadIdx.x;
  if (i < n) out[i] = pool[i] / fmaxf(cnt[i >> 6], 1.f);
}

extern "C" void kernel_launch(void* const* d_in, const int* in_sizes, int n_in,
                              void* d_out, int out_size, void* d_ws, size_t ws_size,
                              hipStream_t stream) {
  const float* x   = (const float*)d_in[0];
  const float* W1  = (const float*)d_in[1];
  const float* as1 = (const float*)d_in[2];
  const float* ad1 = (const float*)d_in[3];
  const float* b1  = (const float*)d_in[4];
  const float* W2  = (const float*)d_in[5];
  const float* as2 = (const float*)d_in[6];
  const float* ad2 = (const float*)d_in[7];
  const float* b2  = (const float*)d_in[8];
  const int* ei    = (const int*)d_in[9];
  const int* batch = (const int*)d_in[10];
  float* out = (float*)d_out;
  const int N = in_sizes[10];      // 100000
  const int E = in_sizes[9] / 2;   // 1600000
  const int NCHUNK = (N + 1023) / 1024;

  // workspace layout (floats), with reuse:
  float* ws   = (float*)d_ws;
  float* xl   = ws;                         // [N*128] layer1 proj
  float* h    = ws + (size_t)N * 128;       // [N*128] layer1 output
  float* xl2  = xl;                         // [N*64]  layer2 proj (xl dead)
  float* es1  = ws + (size_t)N * 256;       // [N*8]
  float* ed1  = es1 + (size_t)N * 8;        // [N*8]
  float* es2  = es1;                        // [N] (es1 dead after gather_h8)
  float* ed2  = es1 + N;                    // [N]
  float* pool = ws + (size_t)N * 272;       // [256*64]
  float* cnt  = pool + 16384;               // [256]
  int* rowptr = (int*)(cnt + 256);          // [N]
  int* csr    = rowptr + N;                 // [E]
  int* ctot   = csr + E;                    // [NCHUNK]

  // ---- CSR build (dst-grouped) ----
  zero_int<<<(N + 255) / 256, 256, 0, stream>>>(rowptr, N);
  count_deg<<<(E + 255) / 256, 256, 0, stream>>>(ei, E, rowptr);
  scanA<<<NCHUNK, 256, 0, stream>>>(rowptr, ctot, N);
  scanB<<<1, 128, 0, stream>>>(ctot, NCHUNK);
  scanC<<<(N + 255) / 256, 256, 0, stream>>>(rowptr, ctot, N);
  fill_csr<<<(E + 255) / 256, 256, 0, stream>>>(ei, E, rowptr, csr);

  // ---- layer 1 ----
  gemm_rm<128, 32, 64><<<(N + 31) / 32, 256, 0, stream>>>(x, W1, xl, N);
  att_h8<<<(N + 1) / 2, 256, 0, stream>>>(xl, as1, ad1, es1, ed1, N);
  gather_h8<<<(N + 3) / 4, 256, 0, stream>>>(xl, es1, ed1, rowptr, csr, b1, h, N);

  // ---- layer 2 ----
  gemm_rm<64, 64, 128><<<(N + 63) / 64, 256, 0, stream>>>(h, W2, xl2, N);
  att_h1<<<(N + 3) / 4, 256, 0, stream>>>(xl2, as2, ad2, es2, ed2, N);
  zeropool<<<(16384 + 256 + 255) / 256, 256, 0, stream>>>(pool, 16384 + 256);
  gather_h1_pool<<<(N + 3) / 4, 256, 0, stream>>>(xl2, es2, ed2, rowptr, csr, b2,
                                                  batch, pool, cnt, N);

  // ---- output ----
  finalout<<<64, 256, 0, stream>>>(pool, cnt, out, 16384);
}

// Round 4
// 590.257 us; speedup vs baseline: 3.1573x; 1.6453x over previous
//
#include <hip/hip_runtime.h>

// GAT 2-layer forward, MI355X. N=100000, E=1.6M (+N self-loops), Fin=128,
// H=8, C=16 (H*C=128), Fout=64, 256 graphs.
//
// Round 4: kill pool atomic contention — gather_h1 does plain stores of the
// per-node vector; pool_seg (1 block/graph, binary-search sorted batch)
// does the segmented mean without any atomics.

#define LRELU_SLOPE 0.2f

__device__ __forceinline__ float lrelu(float x) { return x > 0.f ? x : LRELU_SLOPE * x; }

// ---------------- GEMM: Y[N][M_] = X[N][128] @ W[128][M_], f32 vector ALU ----
template<int M_, int BM, int KB>
__global__ __launch_bounds__(256) void gemm_rm(const float* __restrict__ X,
    const float* __restrict__ W, float* __restrict__ Y, int N) {
  constexpr int K = 128;
  constexpr int NTX = M_ / 4;        // col-groups of 4
  constexpr int NTY = 256 / NTX;
  constexpr int RT  = BM / NTY;      // rows per thread
  __shared__ float Wl[KB * M_];
  __shared__ float Xl[BM * (K + 1)];
  const int tid  = threadIdx.x;
  const int row0 = blockIdx.x * BM;

  for (int i = tid; i < BM * (K / 4); i += 256) {
    const int r = i / (K / 4), c4 = i % (K / 4);
    int gr = row0 + r; if (gr >= N) gr = N - 1;
    const float4 v = ((const float4*)(X + (size_t)gr * K))[c4];
    float* d = &Xl[r * (K + 1) + c4 * 4];
    d[0] = v.x; d[1] = v.y; d[2] = v.z; d[3] = v.w;
  }
  const int tx = tid % NTX, ty = tid / NTX;
  float4 acc[RT];
#pragma unroll
  for (int i = 0; i < RT; ++i) acc[i] = make_float4(0.f, 0.f, 0.f, 0.f);

  for (int kb = 0; kb < K; kb += KB) {
    __syncthreads();
    for (int i = tid; i < KB * M_ / 4; i += 256)
      ((float4*)Wl)[i] = ((const float4*)(W + (size_t)kb * M_))[i];
    __syncthreads();
#pragma unroll 8
    for (int k = 0; k < KB; ++k) {
      const float4 w = *(const float4*)&Wl[k * M_ + tx * 4];
#pragma unroll
      for (int i = 0; i < RT; ++i) {
        const float xv = Xl[(ty * RT + i) * (K + 1) + kb + k];
        acc[i].x += xv * w.x; acc[i].y += xv * w.y;
        acc[i].z += xv * w.z; acc[i].w += xv * w.w;
      }
    }
  }
#pragma unroll
  for (int i = 0; i < RT; ++i) {
    const int gr = row0 + ty * RT + i;
    if (gr < N) ((float4*)(Y + (size_t)gr * M_))[tx] = acc[i];
  }
}

// ---------------- attention scalars ----------------------------------------
__global__ __launch_bounds__(256) void att_h8(const float* __restrict__ xl,
    const float* __restrict__ as, const float* __restrict__ ad,
    float* __restrict__ es, float* __restrict__ ed, int N) {
  const int n = blockIdx.x * 2 + (threadIdx.x >> 7);
  const int c = threadIdx.x & 127;
  if (n >= N) return;
  const float v = xl[(size_t)n * 128 + c];
  float ps = v * as[c];
  float pd = v * ad[c];
#pragma unroll
  for (int o = 8; o >= 1; o >>= 1) {
    ps += __shfl_xor(ps, o, 16);
    pd += __shfl_xor(pd, o, 16);
  }
  if ((c & 15) == 0) {
    es[n * 8 + (c >> 4)] = ps;
    ed[n * 8 + (c >> 4)] = pd;
  }
}

__global__ __launch_bounds__(256) void att_h1(const float* __restrict__ xl2,
    const float* __restrict__ as, const float* __restrict__ ad,
    float* __restrict__ es, float* __restrict__ ed, int N) {
  const int n = blockIdx.x * 4 + (threadIdx.x >> 6);
  const int c = threadIdx.x & 63;
  if (n >= N) return;
  const float v = xl2[(size_t)n * 64 + c];
  float ps = v * as[c];
  float pd = v * ad[c];
#pragma unroll
  for (int o = 32; o >= 1; o >>= 1) {
    ps += __shfl_xor(ps, o, 64);
    pd += __shfl_xor(pd, o, 64);
  }
  if (c == 0) { es[n] = ps; ed[n] = pd; }
}

// ---------------- CSR build --------------------------------------------------
__global__ __launch_bounds__(256) void zero_int(int* __restrict__ p, int n) {
  const int i = blockIdx.x * 256 + threadIdx.x;
  if (i < n) p[i] = 0;
}

__global__ __launch_bounds__(256) void count_deg(const int* __restrict__ ei, int E,
    int* __restrict__ deg) {
  const int e = blockIdx.x * 256 + threadIdx.x;
  if (e < E) atomicAdd(&deg[ei[E + e]], 1);
}

__global__ __launch_bounds__(256) void scanA(int* __restrict__ a, int* __restrict__ ctot, int N) {
  __shared__ int sm[256];
  const int base = blockIdx.x * 1024;
  const int t = threadIdx.x;
  int v[4], s = 0;
#pragma unroll
  for (int i = 0; i < 4; ++i) {
    const int idx = base + t * 4 + i;
    v[i] = (idx < N) ? a[idx] : 0;
    s += v[i];
  }
  sm[t] = s;
  __syncthreads();
  for (int o = 1; o < 256; o <<= 1) {
    const int x = (t >= o) ? sm[t - o] : 0;
    __syncthreads();
    sm[t] += x;
    __syncthreads();
  }
  if (t == 255) ctot[blockIdx.x] = sm[255];
  int run = sm[t] - s;
#pragma unroll
  for (int i = 0; i < 4; ++i) {
    const int idx = base + t * 4 + i;
    if (idx < N) a[idx] = run;
    run += v[i];
  }
}

__global__ __launch_bounds__(128) void scanB(int* __restrict__ ctot, int n) {
  __shared__ int sm[128];
  const int t = threadIdx.x;
  const int v = (t < n) ? ctot[t] : 0;
  sm[t] = v;
  __syncthreads();
  for (int o = 1; o < 128; o <<= 1) {
    const int x = (t >= o) ? sm[t - o] : 0;
    __syncthreads();
    sm[t] += x;
    __syncthreads();
  }
  if (t < n) ctot[t] = sm[t] - v;
}

__global__ __launch_bounds__(256) void scanC(int* __restrict__ a, const int* __restrict__ ctot, int N) {
  const int i = blockIdx.x * 256 + threadIdx.x;
  if (i < N) a[i] += ctot[i >> 10];
}

// post-fill: rowptr[n] == end of node n; start = (n==0)?0:rowptr[n-1]
__global__ __launch_bounds__(256) void fill_csr(const int* __restrict__ ei, int E,
    int* __restrict__ rowptr, int* __restrict__ csr) {
  const int e = blockIdx.x * 256 + threadIdx.x;
  if (e < E) {
    const int slot = atomicAdd(&rowptr[ei[E + e]], 1);
    csr[slot] = ei[e];
  }
}

// ---------------- layer-1 gather (prefetched): one wave per dst node --------
__global__ __launch_bounds__(256) void gather_h8(const float* __restrict__ xl,
    const float* __restrict__ es, const float* __restrict__ ed,
    const int* __restrict__ rowptr, const int* __restrict__ csr,
    const float* __restrict__ bias, float* __restrict__ hout, int N) {
  const int wave = threadIdx.x >> 6, lane = threadIdx.x & 63;
  const int n = blockIdx.x * 4 + wave;
  if (n >= N) return;
  const int h = lane >> 3;
  const float edv = ed[n * 8 + h];
  const int start = (n == 0) ? 0 : rowptr[n - 1];
  const int end = rowptr[n];

  float2 acc;
  float ssum;
  {  // self loop
    const float ee = __expf(lrelu(es[n * 8 + h] + edv));
    const float2 xv = *(const float2*)&xl[(size_t)n * 128 + lane * 2];
    acc.x = ee * xv.x; acc.y = ee * xv.y; ssum = ee;
  }
  constexpr int P = 8;
  int j = start;
  for (; j + P <= end; j += P) {
    int srcs[P];
#pragma unroll
    for (int k = 0; k < P; ++k) srcs[k] = csr[j + k];
    float ev[P];
    float2 xv[P];
#pragma unroll
    for (int k = 0; k < P; ++k) {
      ev[k] = es[srcs[k] * 8 + h];
      xv[k] = *(const float2*)&xl[(size_t)srcs[k] * 128 + lane * 2];
    }
#pragma unroll
    for (int k = 0; k < P; ++k) {
      const float ee = __expf(lrelu(ev[k] + edv));
      acc.x += ee * xv[k].x; acc.y += ee * xv[k].y; ssum += ee;
    }
  }
  for (; j < end; ++j) {
    const int src = csr[j];
    const float ee = __expf(lrelu(es[src * 8 + h] + edv));
    const float2 xv = *(const float2*)&xl[(size_t)src * 128 + lane * 2];
    acc.x += ee * xv.x; acc.y += ee * xv.y; ssum += ee;
  }
  const float inv = 1.f / (ssum + 1e-16f);
  const int c = lane * 2;
  float v0 = acc.x * inv + bias[c];
  float v1 = acc.y * inv + bias[c + 1];
  v0 = v0 > 0.f ? v0 : __expf(v0) - 1.f;
  v1 = v1 > 0.f ? v1 : __expf(v1) - 1.f;
  *(float2*)&hout[(size_t)n * 128 + c] = make_float2(v0, v1);
}

// ---------------- layer-2 gather (prefetched), plain store ------------------
__global__ __launch_bounds__(256) void gather_h1(const float* __restrict__ xl2,
    const float* __restrict__ es, const float* __restrict__ ed,
    const int* __restrict__ rowptr, const int* __restrict__ csr,
    const float* __restrict__ bias, float* __restrict__ vout, int N) {
  const int wave = threadIdx.x >> 6, lane = threadIdx.x & 63;
  const int n = blockIdx.x * 4 + wave;
  if (n >= N) return;
  const float edv = ed[n];
  const int start = (n == 0) ? 0 : rowptr[n - 1];
  const int end = rowptr[n];

  float ee0 = __expf(lrelu(es[n] + edv));          // self loop
  float acc = ee0 * xl2[(size_t)n * 64 + lane];
  float ssum = ee0;
  constexpr int P = 8;
  int j = start;
  for (; j + P <= end; j += P) {
    int srcs[P];
#pragma unroll
    for (int k = 0; k < P; ++k) srcs[k] = csr[j + k];
    float ev[P], xv[P];
#pragma unroll
    for (int k = 0; k < P; ++k) {
      ev[k] = es[srcs[k]];
      xv[k] = xl2[(size_t)srcs[k] * 64 + lane];
    }
#pragma unroll
    for (int k = 0; k < P; ++k) {
      const float e2 = __expf(lrelu(ev[k] + edv));
      acc += e2 * xv[k]; ssum += e2;
    }
  }
  for (; j < end; ++j) {
    const int src = csr[j];
    const float e2 = __expf(lrelu(es[src] + edv));
    acc += e2 * xl2[(size_t)src * 64 + lane];
    ssum += e2;
  }
  vout[(size_t)n * 64 + lane] = acc / (ssum + 1e-16f) + bias[lane];
}

// ---------------- segmented mean pool: 1 block per graph --------------------
__global__ __launch_bounds__(256) void pool_seg(const float* __restrict__ v,
    const int* __restrict__ batch, float* __restrict__ out, int N) {
  const int g = blockIdx.x;
  const int t = threadIdx.x;
  // start = lower_bound(batch, g); end = lower_bound(batch, g+1)
  int lo = 0, hi = N;
  while (lo < hi) { const int m = (lo + hi) >> 1; if (batch[m] < g) lo = m + 1; else hi = m; }
  const int start = lo;
  hi = N;
  while (lo < hi) { const int m = (lo + hi) >> 1; if (batch[m] <= g) lo = m + 1; else hi = m; }
  const int end = lo;

  const int c = t & 63, rg = t >> 6;
  float s = 0.f;
  for (int r = start + rg; r < end; r += 4) s += v[(size_t)r * 64 + c];
  __shared__ float sm[256];
  sm[t] = s;
  __syncthreads();
  if (t < 64) {
    const float tot = sm[t] + sm[t + 64] + sm[t + 128] + sm[t + 192];
    out[g * 64 + t] = tot / fmaxf((float)(end - start), 1.f);
  }
}

extern "C" void kernel_launch(void* const* d_in, const int* in_sizes, int n_in,
                              void* d_out, int out_size, void* d_ws, size_t ws_size,
                              hipStream_t stream) {
  const float* x   = (const float*)d_in[0];
  const float* W1  = (const float*)d_in[1];
  const float* as1 = (const float*)d_in[2];
  const float* ad1 = (const float*)d_in[3];
  const float* b1  = (const float*)d_in[4];
  const float* W2  = (const float*)d_in[5];
  const float* as2 = (const float*)d_in[6];
  const float* ad2 = (const float*)d_in[7];
  const float* b2  = (const float*)d_in[8];
  const int* ei    = (const int*)d_in[9];
  const int* batch = (const int*)d_in[10];
  float* out = (float*)d_out;
  const int N = in_sizes[10];      // 100000
  const int E = in_sizes[9] / 2;   // 1600000
  const int G = out_size / 64;     // 256 graphs
  const int NCHUNK = (N + 1023) / 1024;

  // workspace layout (floats), with reuse:
  float* ws   = (float*)d_ws;
  float* xl   = ws;                         // [N*128] layer1 proj
  float* h    = ws + (size_t)N * 128;       // [N*128] layer1 output
  float* xl2  = xl;                         // [N*64]  layer2 proj (xl dead)
  float* vbuf = h;                          // [N*64]  layer2 node vec (h dead)
  float* es1  = ws + (size_t)N * 256;       // [N*8]
  float* ed1  = es1 + (size_t)N * 8;        // [N*8]
  float* es2  = es1;                        // [N] (es1 dead after gather_h8)
  float* ed2  = es1 + N;                    // [N]
  int* rowptr = (int*)(ws + (size_t)N * 272); // [N]
  int* csr    = rowptr + N;                 // [E]
  int* ctot   = csr + E;                    // [NCHUNK]

  // ---- CSR build (dst-grouped) ----
  zero_int<<<(N + 255) / 256, 256, 0, stream>>>(rowptr, N);
  count_deg<<<(E + 255) / 256, 256, 0, stream>>>(ei, E, rowptr);
  scanA<<<NCHUNK, 256, 0, stream>>>(rowptr, ctot, N);
  scanB<<<1, 128, 0, stream>>>(ctot, NCHUNK);
  scanC<<<(N + 255) / 256, 256, 0, stream>>>(rowptr, ctot, N);
  fill_csr<<<(E + 255) / 256, 256, 0, stream>>>(ei, E, rowptr, csr);

  // ---- layer 1 ----
  gemm_rm<128, 32, 64><<<(N + 31) / 32, 256, 0, stream>>>(x, W1, xl, N);
  att_h8<<<(N + 1) / 2, 256, 0, stream>>>(xl, as1, ad1, es1, ed1, N);
  gather_h8<<<(N + 3) / 4, 256, 0, stream>>>(xl, es1, ed1, rowptr, csr, b1, h, N);

  // ---- layer 2 ----
  gemm_rm<64, 64, 128><<<(N + 63) / 64, 256, 0, stream>>>(h, W2, xl2, N);
  att_h1<<<(N + 3) / 4, 256, 0, stream>>>(xl2, as2, ad2, es2, ed2, N);
  gather_h1<<<(N + 3) / 4, 256, 0, stream>>>(xl2, es2, ed2, rowptr, csr, b2, vbuf, N);

  // ---- global mean pool (segmented, no atomics) ----
  pool_seg<<<G, 256, 0, stream>>>(vbuf, batch, out, N);
}

// Round 5
// 530.490 us; speedup vs baseline: 3.5130x; 1.1127x over previous
//
#include <hip/hip_runtime.h>
#include <hip/hip_fp16.h>

// GAT 2-layer forward, MI355X. N=100000, E=1.6M (+N self-loops), Fin=128,
// H=8, C=16 (H*C=128), Fout=64, 256 graphs.
//
// Round 5: (a) f16 storage for gathered payloads (xl, h, xl2) — halves the
// dominant gather traffic; (b) 4-edge-batched CSR build kernels for 4x MLP
// on the latency-bound atomic chains.

#define LRELU_SLOPE 0.2f

__device__ __forceinline__ float lrelu(float x) { return x > 0.f ? x : LRELU_SLOPE * x; }

// ---------------- GEMM: Y[N][M_](f16) = X[N][128] @ W[128][M_] --------------
template<typename TX, int M_, int BM, int KB>
__global__ __launch_bounds__(256) void gemm_rm(const TX* __restrict__ X,
    const float* __restrict__ W, __half* __restrict__ Y, int N) {
  constexpr int K = 128;
  constexpr int NTX = M_ / 4;        // col-groups of 4
  constexpr int NTY = 256 / NTX;
  constexpr int RT  = BM / NTY;      // rows per thread
  __shared__ float Wl[KB * M_];
  __shared__ float Xl[BM * (K + 1)];
  const int tid  = threadIdx.x;
  const int row0 = blockIdx.x * BM;

  if constexpr (sizeof(TX) == 4) {   // f32 input
    for (int i = tid; i < BM * (K / 4); i += 256) {
      const int r = i / (K / 4), c4 = i % (K / 4);
      int gr = row0 + r; if (gr >= N) gr = N - 1;
      const float4 v = ((const float4*)((const float*)X + (size_t)gr * K))[c4];
      float* d = &Xl[r * (K + 1) + c4 * 4];
      d[0] = v.x; d[1] = v.y; d[2] = v.z; d[3] = v.w;
    }
  } else {                           // f16 input
    for (int i = tid; i < BM * (K / 8); i += 256) {
      const int r = i / (K / 8), c8 = i % (K / 8);
      int gr = row0 + r; if (gr >= N) gr = N - 1;
      const __half2* s = (const __half2*)((const __half*)X + (size_t)gr * K + c8 * 8);
      float* d = &Xl[r * (K + 1) + c8 * 8];
#pragma unroll
      for (int q = 0; q < 4; ++q) {
        const float2 f = __half22float2(s[q]);
        d[2 * q] = f.x; d[2 * q + 1] = f.y;
      }
    }
  }
  const int tx = tid % NTX, ty = tid / NTX;
  float4 acc[RT];
#pragma unroll
  for (int i = 0; i < RT; ++i) acc[i] = make_float4(0.f, 0.f, 0.f, 0.f);

  for (int kb = 0; kb < K; kb += KB) {
    __syncthreads();
    for (int i = tid; i < KB * M_ / 4; i += 256)
      ((float4*)Wl)[i] = ((const float4*)(W + (size_t)kb * M_))[i];
    __syncthreads();
#pragma unroll 8
    for (int k = 0; k < KB; ++k) {
      const float4 w = *(const float4*)&Wl[k * M_ + tx * 4];
#pragma unroll
      for (int i = 0; i < RT; ++i) {
        const float xv = Xl[(ty * RT + i) * (K + 1) + kb + k];
        acc[i].x += xv * w.x; acc[i].y += xv * w.y;
        acc[i].z += xv * w.z; acc[i].w += xv * w.w;
      }
    }
  }
#pragma unroll
  for (int i = 0; i < RT; ++i) {
    const int gr = row0 + ty * RT + i;
    if (gr < N) {
      __half2* dst = (__half2*)(Y + (size_t)gr * M_ + tx * 4);
      dst[0] = __floats2half2_rn(acc[i].x, acc[i].y);
      dst[1] = __floats2half2_rn(acc[i].z, acc[i].w);
    }
  }
}

// ---------------- attention scalars (f16 input) -----------------------------
__global__ __launch_bounds__(256) void att_h8(const __half* __restrict__ xl,
    const float* __restrict__ as, const float* __restrict__ ad,
    float* __restrict__ es, float* __restrict__ ed, int N) {
  const int n = blockIdx.x * 2 + (threadIdx.x >> 7);
  const int c = threadIdx.x & 127;
  if (n >= N) return;
  const float v = __half2float(xl[(size_t)n * 128 + c]);
  float ps = v * as[c];
  float pd = v * ad[c];
#pragma unroll
  for (int o = 8; o >= 1; o >>= 1) {
    ps += __shfl_xor(ps, o, 16);
    pd += __shfl_xor(pd, o, 16);
  }
  if ((c & 15) == 0) {
    es[n * 8 + (c >> 4)] = ps;
    ed[n * 8 + (c >> 4)] = pd;
  }
}

__global__ __launch_bounds__(256) void att_h1(const __half* __restrict__ xl2,
    const float* __restrict__ as, const float* __restrict__ ad,
    float* __restrict__ es, float* __restrict__ ed, int N) {
  const int n = blockIdx.x * 4 + (threadIdx.x >> 6);
  const int c = threadIdx.x & 63;
  if (n >= N) return;
  const float v = __half2float(xl2[(size_t)n * 64 + c]);
  float ps = v * as[c];
  float pd = v * ad[c];
#pragma unroll
  for (int o = 32; o >= 1; o >>= 1) {
    ps += __shfl_xor(ps, o, 64);
    pd += __shfl_xor(pd, o, 64);
  }
  if (c == 0) { es[n] = ps; ed[n] = pd; }
}

// ---------------- CSR build --------------------------------------------------
__global__ __launch_bounds__(256) void zero_int(int* __restrict__ p, int n) {
  const int i = blockIdx.x * 256 + threadIdx.x;
  if (i < n) p[i] = 0;
}

// 4 edges/thread: independent atomics for MLP
__global__ __launch_bounds__(256) void count_deg4(const int* __restrict__ ei, int E,
    int* __restrict__ deg) {
  const int base = (blockIdx.x * 256 + threadIdx.x) * 4;
  if (base + 4 <= E) {
    const int4 d4 = *(const int4*)&ei[E + base];
    atomicAdd(&deg[d4.x], 1);
    atomicAdd(&deg[d4.y], 1);
    atomicAdd(&deg[d4.z], 1);
    atomicAdd(&deg[d4.w], 1);
  } else {
    for (int e = base; e < E; ++e) atomicAdd(&deg[ei[E + e]], 1);
  }
}

__global__ __launch_bounds__(256) void scanA(int* __restrict__ a, int* __restrict__ ctot, int N) {
  __shared__ int sm[256];
  const int base = blockIdx.x * 1024;
  const int t = threadIdx.x;
  int v[4], s = 0;
#pragma unroll
  for (int i = 0; i < 4; ++i) {
    const int idx = base + t * 4 + i;
    v[i] = (idx < N) ? a[idx] : 0;
    s += v[i];
  }
  sm[t] = s;
  __syncthreads();
  for (int o = 1; o < 256; o <<= 1) {
    const int x = (t >= o) ? sm[t - o] : 0;
    __syncthreads();
    sm[t] += x;
    __syncthreads();
  }
  if (t == 255) ctot[blockIdx.x] = sm[255];
  int run = sm[t] - s;
#pragma unroll
  for (int i = 0; i < 4; ++i) {
    const int idx = base + t * 4 + i;
    if (idx < N) a[idx] = run;
    run += v[i];
  }
}

__global__ __launch_bounds__(128) void scanB(int* __restrict__ ctot, int n) {
  __shared__ int sm[128];
  const int t = threadIdx.x;
  const int v = (t < n) ? ctot[t] : 0;
  sm[t] = v;
  __syncthreads();
  for (int o = 1; o < 128; o <<= 1) {
    const int x = (t >= o) ? sm[t - o] : 0;
    __syncthreads();
    sm[t] += x;
    __syncthreads();
  }
  if (t < n) ctot[t] = sm[t] - v;
}

__global__ __launch_bounds__(256) void scanC(int* __restrict__ a, const int* __restrict__ ctot, int N) {
  const int i = blockIdx.x * 256 + threadIdx.x;
  if (i < N) a[i] += ctot[i >> 10];
}

// post-fill: rowptr[n] == end of node n; start = (n==0)?0:rowptr[n-1]
__global__ __launch_bounds__(256) void fill_csr4(const int* __restrict__ ei, int E,
    int* __restrict__ rowptr, int* __restrict__ csr) {
  const int base = (blockIdx.x * 256 + threadIdx.x) * 4;
  if (base + 4 <= E) {
    const int4 s4 = *(const int4*)&ei[base];
    const int4 d4 = *(const int4*)&ei[E + base];
    const int a0 = atomicAdd(&rowptr[d4.x], 1);
    const int a1 = atomicAdd(&rowptr[d4.y], 1);
    const int a2 = atomicAdd(&rowptr[d4.z], 1);
    const int a3 = atomicAdd(&rowptr[d4.w], 1);
    csr[a0] = s4.x; csr[a1] = s4.y; csr[a2] = s4.z; csr[a3] = s4.w;
  } else {
    for (int e = base; e < E; ++e) {
      const int slot = atomicAdd(&rowptr[ei[E + e]], 1);
      csr[slot] = ei[e];
    }
  }
}

// ---------------- layer-1 gather (prefetched, f16 payload) ------------------
__global__ __launch_bounds__(256) void gather_h8(const __half* __restrict__ xl,
    const float* __restrict__ es, const float* __restrict__ ed,
    const int* __restrict__ rowptr, const int* __restrict__ csr,
    const float* __restrict__ bias, __half* __restrict__ hout, int N) {
  const int wave = threadIdx.x >> 6, lane = threadIdx.x & 63;
  const int n = blockIdx.x * 4 + wave;
  if (n >= N) return;
  const int h = lane >> 3;
  const float edv = ed[n * 8 + h];
  const int start = (n == 0) ? 0 : rowptr[n - 1];
  const int end = rowptr[n];

  float2 acc;
  float ssum;
  {  // self loop
    const float ee = __expf(lrelu(es[n * 8 + h] + edv));
    const float2 xv = __half22float2(*(const __half2*)&xl[(size_t)n * 128 + lane * 2]);
    acc.x = ee * xv.x; acc.y = ee * xv.y; ssum = ee;
  }
  constexpr int P = 8;
  int j = start;
  for (; j + P <= end; j += P) {
    int srcs[P];
#pragma unroll
    for (int k = 0; k < P; ++k) srcs[k] = csr[j + k];
    float ev[P];
    __half2 xv[P];
#pragma unroll
    for (int k = 0; k < P; ++k) {
      ev[k] = es[srcs[k] * 8 + h];
      xv[k] = *(const __half2*)&xl[(size_t)srcs[k] * 128 + lane * 2];
    }
#pragma unroll
    for (int k = 0; k < P; ++k) {
      const float ee = __expf(lrelu(ev[k] + edv));
      const float2 f = __half22float2(xv[k]);
      acc.x += ee * f.x; acc.y += ee * f.y; ssum += ee;
    }
  }
  for (; j < end; ++j) {
    const int src = csr[j];
    const float ee = __expf(lrelu(es[src * 8 + h] + edv));
    const float2 f = __half22float2(*(const __half2*)&xl[(size_t)src * 128 + lane * 2]);
    acc.x += ee * f.x; acc.y += ee * f.y; ssum += ee;
  }
  const float inv = 1.f / (ssum + 1e-16f);
  const int c = lane * 2;
  float v0 = acc.x * inv + bias[c];
  float v1 = acc.y * inv + bias[c + 1];
  v0 = v0 > 0.f ? v0 : __expf(v0) - 1.f;
  v1 = v1 > 0.f ? v1 : __expf(v1) - 1.f;
  *(__half2*)&hout[(size_t)n * 128 + c] = __floats2half2_rn(v0, v1);
}

// ---------------- layer-2 gather (prefetched, f16 payload), plain store -----
__global__ __launch_bounds__(256) void gather_h1(const __half* __restrict__ xl2,
    const float* __restrict__ es, const float* __restrict__ ed,
    const int* __restrict__ rowptr, const int* __restrict__ csr,
    const float* __restrict__ bias, float* __restrict__ vout, int N) {
  const int wave = threadIdx.x >> 6, lane = threadIdx.x & 63;
  const int n = blockIdx.x * 4 + wave;
  if (n >= N) return;
  const float edv = ed[n];
  const int start = (n == 0) ? 0 : rowptr[n - 1];
  const int end = rowptr[n];

  float ee0 = __expf(lrelu(es[n] + edv));          // self loop
  float acc = ee0 * __half2float(xl2[(size_t)n * 64 + lane]);
  float ssum = ee0;
  constexpr int P = 8;
  int j = start;
  for (; j + P <= end; j += P) {
    int srcs[P];
#pragma unroll
    for (int k = 0; k < P; ++k) srcs[k] = csr[j + k];
    float ev[P];
    __half xv[P];
#pragma unroll
    for (int k = 0; k < P; ++k) {
      ev[k] = es[srcs[k]];
      xv[k] = xl2[(size_t)srcs[k] * 64 + lane];
    }
#pragma unroll
    for (int k = 0; k < P; ++k) {
      const float e2 = __expf(lrelu(ev[k] + edv));
      acc += e2 * __half2float(xv[k]); ssum += e2;
    }
  }
  for (; j < end; ++j) {
    const int src = csr[j];
    const float e2 = __expf(lrelu(es[src] + edv));
    acc += e2 * __half2float(xl2[(size_t)src * 64 + lane]);
    ssum += e2;
  }
  vout[(size_t)n * 64 + lane] = acc / (ssum + 1e-16f) + bias[lane];
}

// ---------------- segmented mean pool: 1 block per graph --------------------
__global__ __launch_bounds__(256) void pool_seg(const float* __restrict__ v,
    const int* __restrict__ batch, float* __restrict__ out, int N) {
  const int g = blockIdx.x;
  const int t = threadIdx.x;
  int lo = 0, hi = N;
  while (lo < hi) { const int m = (lo + hi) >> 1; if (batch[m] < g) lo = m + 1; else hi = m; }
  const int start = lo;
  hi = N;
  while (lo < hi) { const int m = (lo + hi) >> 1; if (batch[m] <= g) lo = m + 1; else hi = m; }
  const int end = lo;

  const int c = t & 63, rg = t >> 6;
  float s = 0.f;
  for (int r = start + rg; r < end; r += 4) s += v[(size_t)r * 64 + c];
  __shared__ float sm[256];
  sm[t] = s;
  __syncthreads();
  if (t < 64) {
    const float tot = sm[t] + sm[t + 64] + sm[t + 128] + sm[t + 192];
    out[g * 64 + t] = tot / fmaxf((float)(end - start), 1.f);
  }
}

extern "C" void kernel_launch(void* const* d_in, const int* in_sizes, int n_in,
                              void* d_out, int out_size, void* d_ws, size_t ws_size,
                              hipStream_t stream) {
  const float* x   = (const float*)d_in[0];
  const float* W1  = (const float*)d_in[1];
  const float* as1 = (const float*)d_in[2];
  const float* ad1 = (const float*)d_in[3];
  const float* b1  = (const float*)d_in[4];
  const float* W2  = (const float*)d_in[5];
  const float* as2 = (const float*)d_in[6];
  const float* ad2 = (const float*)d_in[7];
  const float* b2  = (const float*)d_in[8];
  const int* ei    = (const int*)d_in[9];
  const int* batch = (const int*)d_in[10];
  float* out = (float*)d_out;
  const int N = in_sizes[10];      // 100000
  const int E = in_sizes[9] / 2;   // 1600000
  const int G = out_size / 64;     // 256 graphs
  const int NCHUNK = (N + 1023) / 1024;

  // workspace layout (bytes), with reuse:
  char* ws = (char*)d_ws;
  __half* xl  = (__half*)ws;                         // [N*128] f16, layer1 proj
  __half* h   = (__half*)(ws + (size_t)N * 256);     // [N*128] f16, layer1 out
  __half* xl2 = xl;                                  // [N*64] f16 (xl dead)
  float* vbuf = (float*)(ws + (size_t)N * 256);      // [N*64] f32 (h dead after gemm2)
  float* es1  = (float*)(ws + (size_t)N * 512);      // [N*8]
  float* ed1  = es1 + (size_t)N * 8;                 // [N*8]
  float* es2  = es1;                                 // [N]
  float* ed2  = es1 + N;                             // [N]
  int* rowptr = (int*)(ed1 + (size_t)N * 8);         // [N]
  int* csr    = rowptr + N;                          // [E]
  int* ctot   = csr + E;                             // [NCHUNK]

  // ---- CSR build (dst-grouped) ----
  zero_int<<<(N + 255) / 256, 256, 0, stream>>>(rowptr, N);
  count_deg4<<<((E + 3) / 4 + 255) / 256, 256, 0, stream>>>(ei, E, rowptr);
  scanA<<<NCHUNK, 256, 0, stream>>>(rowptr, ctot, N);
  scanB<<<1, 128, 0, stream>>>(ctot, NCHUNK);
  scanC<<<(N + 255) / 256, 256, 0, stream>>>(rowptr, ctot, N);
  fill_csr4<<<((E + 3) / 4 + 255) / 256, 256, 0, stream>>>(ei, E, rowptr, csr);

  // ---- layer 1 ----
  gemm_rm<float, 128, 32, 64><<<(N + 31) / 32, 256, 0, stream>>>(x, W1, xl, N);
  att_h8<<<(N + 1) / 2, 256, 0, stream>>>(xl, as1, ad1, es1, ed1, N);
  gather_h8<<<(N + 3) / 4, 256, 0, stream>>>(xl, es1, ed1, rowptr, csr, b1, h, N);

  // ---- layer 2 ----
  gemm_rm<__half, 64, 64, 128><<<(N + 63) / 64, 256, 0, stream>>>(h, W2, xl2, N);
  att_h1<<<(N + 3) / 4, 256, 0, stream>>>(xl2, as2, ad2, es2, ed2, N);
  gather_h1<<<(N + 3) / 4, 256, 0, stream>>>(xl2, es2, ed2, rowptr, csr, b2, vbuf, N);

  // ---- global mean pool (segmented, no atomics) ----
  pool_seg<<<G, 256, 0, stream>>>(vbuf, batch, out, N);
}

// Round 6
// 370.898 us; speedup vs baseline: 5.0245x; 1.4303x over previous
//
#include <hip/hip_runtime.h>
#include <hip/hip_fp16.h>

// GAT 2-layer forward, MI355X. N=100000, E=1.6M (+N self-loops), Fin=128,
// H=8, C=16 (H*C=128), Fout=64, 256 graphs.
//
// Round 6: CSR build via two-level LDS counting sort (no global atomics).
// Round-5 evidence: 1.6M device-scope atomicAdds = 107MB of 64B-granule
// coherent RMW traffic = 136us wall. Bucket by dst>>9 (512 nodes/bucket),
// all counting/offsets in LDS.

#define LRELU_SLOPE 0.2f
#define NBLKB 512          // bucketing blocks
#define NBUCK 256          // buckets (dst>>9, N<=131072)

__device__ __forceinline__ float lrelu(float x) { return x > 0.f ? x : LRELU_SLOPE * x; }

// ---------------- GEMM: Y[N][M_](f16) = X[N][128] @ W[128][M_] --------------
template<typename TX, int M_, int BM, int KB>
__global__ __launch_bounds__(256) void gemm_rm(const TX* __restrict__ X,
    const float* __restrict__ W, __half* __restrict__ Y, int N) {
  constexpr int K = 128;
  constexpr int NTX = M_ / 4;
  constexpr int NTY = 256 / NTX;
  constexpr int RT  = BM / NTY;
  __shared__ float Wl[KB * M_];
  __shared__ float Xl[BM * (K + 1)];
  const int tid  = threadIdx.x;
  const int row0 = blockIdx.x * BM;

  if constexpr (sizeof(TX) == 4) {
    for (int i = tid; i < BM * (K / 4); i += 256) {
      const int r = i / (K / 4), c4 = i % (K / 4);
      int gr = row0 + r; if (gr >= N) gr = N - 1;
      const float4 v = ((const float4*)((const float*)X + (size_t)gr * K))[c4];
      float* d = &Xl[r * (K + 1) + c4 * 4];
      d[0] = v.x; d[1] = v.y; d[2] = v.z; d[3] = v.w;
    }
  } else {
    for (int i = tid; i < BM * (K / 8); i += 256) {
      const int r = i / (K / 8), c8 = i % (K / 8);
      int gr = row0 + r; if (gr >= N) gr = N - 1;
      const __half2* s = (const __half2*)((const __half*)X + (size_t)gr * K + c8 * 8);
      float* d = &Xl[r * (K + 1) + c8 * 8];
#pragma unroll
      for (int q = 0; q < 4; ++q) {
        const float2 f = __half22float2(s[q]);
        d[2 * q] = f.x; d[2 * q + 1] = f.y;
      }
    }
  }
  const int tx = tid % NTX, ty = tid / NTX;
  float4 acc[RT];
#pragma unroll
  for (int i = 0; i < RT; ++i) acc[i] = make_float4(0.f, 0.f, 0.f, 0.f);

  for (int kb = 0; kb < K; kb += KB) {
    __syncthreads();
    for (int i = tid; i < KB * M_ / 4; i += 256)
      ((float4*)Wl)[i] = ((const float4*)(W + (size_t)kb * M_))[i];
    __syncthreads();
#pragma unroll 8
    for (int k = 0; k < KB; ++k) {
      const float4 w = *(const float4*)&Wl[k * M_ + tx * 4];
#pragma unroll
      for (int i = 0; i < RT; ++i) {
        const float xv = Xl[(ty * RT + i) * (K + 1) + kb + k];
        acc[i].x += xv * w.x; acc[i].y += xv * w.y;
        acc[i].z += xv * w.z; acc[i].w += xv * w.w;
      }
    }
  }
#pragma unroll
  for (int i = 0; i < RT; ++i) {
    const int gr = row0 + ty * RT + i;
    if (gr < N) {
      __half2* dst = (__half2*)(Y + (size_t)gr * M_ + tx * 4);
      dst[0] = __floats2half2_rn(acc[i].x, acc[i].y);
      dst[1] = __floats2half2_rn(acc[i].z, acc[i].w);
    }
  }
}

// ---------------- attention scalars (f16 input) -----------------------------
__global__ __launch_bounds__(256) void att_h8(const __half* __restrict__ xl,
    const float* __restrict__ as, const float* __restrict__ ad,
    float* __restrict__ es, float* __restrict__ ed, int N) {
  const int n = blockIdx.x * 2 + (threadIdx.x >> 7);
  const int c = threadIdx.x & 127;
  if (n >= N) return;
  const float v = __half2float(xl[(size_t)n * 128 + c]);
  float ps = v * as[c];
  float pd = v * ad[c];
#pragma unroll
  for (int o = 8; o >= 1; o >>= 1) {
    ps += __shfl_xor(ps, o, 16);
    pd += __shfl_xor(pd, o, 16);
  }
  if ((c & 15) == 0) {
    es[n * 8 + (c >> 4)] = ps;
    ed[n * 8 + (c >> 4)] = pd;
  }
}

__global__ __launch_bounds__(256) void att_h1(const __half* __restrict__ xl2,
    const float* __restrict__ as, const float* __restrict__ ad,
    float* __restrict__ es, float* __restrict__ ed, int N) {
  const int n = blockIdx.x * 4 + (threadIdx.x >> 6);
  const int c = threadIdx.x & 63;
  if (n >= N) return;
  const float v = __half2float(xl2[(size_t)n * 64 + c]);
  float ps = v * as[c];
  float pd = v * ad[c];
#pragma unroll
  for (int o = 32; o >= 1; o >>= 1) {
    ps += __shfl_xor(ps, o, 64);
    pd += __shfl_xor(pd, o, 64);
  }
  if (c == 0) { es[n] = ps; ed[n] = pd; }
}

// ---------------- CSR build: LDS counting sort ------------------------------
// K1: per-block LDS histogram of dst>>9 -> bh[bucket*NBLKB + blk]
__global__ __launch_bounds__(256) void bucket_hist(const int* __restrict__ ei, int E,
    int* __restrict__ bh) {
  __shared__ int hist[NBUCK];
  const int t = threadIdx.x;
  hist[t] = 0;
  __syncthreads();
  const int chunk = (E + NBLKB - 1) / NBLKB;
  const int s0 = blockIdx.x * chunk;
  const int s1 = min(E, s0 + chunk);
  for (int e = s0 + t; e < s1; e += 256) atomicAdd(&hist[ei[E + e] >> 9], 1);
  __syncthreads();
  bh[t * NBLKB + blockIdx.x] = hist[t];
}

// generic scan kernels (1024-chunk hierarchy)
__global__ __launch_bounds__(256) void scanA(int* __restrict__ a, int* __restrict__ ctot, int N) {
  __shared__ int sm[256];
  const int base = blockIdx.x * 1024;
  const int t = threadIdx.x;
  int v[4], s = 0;
#pragma unroll
  for (int i = 0; i < 4; ++i) {
    const int idx = base + t * 4 + i;
    v[i] = (idx < N) ? a[idx] : 0;
    s += v[i];
  }
  sm[t] = s;
  __syncthreads();
  for (int o = 1; o < 256; o <<= 1) {
    const int x = (t >= o) ? sm[t - o] : 0;
    __syncthreads();
    sm[t] += x;
    __syncthreads();
  }
  if (t == 255) ctot[blockIdx.x] = sm[255];
  int run = sm[t] - s;
#pragma unroll
  for (int i = 0; i < 4; ++i) {
    const int idx = base + t * 4 + i;
    if (idx < N) a[idx] = run;
    run += v[i];
  }
}

__global__ __launch_bounds__(128) void scanB(int* __restrict__ ctot, int n) {
  __shared__ int sm[128];
  const int t = threadIdx.x;
  const int v = (t < n) ? ctot[t] : 0;
  sm[t] = v;
  __syncthreads();
  for (int o = 1; o < 128; o <<= 1) {
    const int x = (t >= o) ? sm[t - o] : 0;
    __syncthreads();
    sm[t] += x;
    __syncthreads();
  }
  if (t < n) ctot[t] = sm[t] - v;
}

__global__ __launch_bounds__(256) void scanC(int* __restrict__ a, const int* __restrict__ ctot, int N) {
  const int i = blockIdx.x * 256 + threadIdx.x;
  if (i < N) a[i] += ctot[i >> 10];
}

// K3: scatter (src,dst) into bucket-grouped eb using scanned offsets (LDS atomics)
__global__ __launch_bounds__(256) void bucket_scatter(const int* __restrict__ ei, int E,
    const int* __restrict__ bh, int2* __restrict__ eb) {
  __shared__ int offs[NBUCK];
  const int t = threadIdx.x;
  offs[t] = bh[t * NBLKB + blockIdx.x];
  __syncthreads();
  const int chunk = (E + NBLKB - 1) / NBLKB;
  const int s0 = blockIdx.x * chunk;
  const int s1 = min(E, s0 + chunk);
  for (int e = s0 + t; e < s1; e += 256) {
    const int s = ei[e], d = ei[E + e];
    const int pos = atomicAdd(&offs[d >> 9], 1);
    eb[pos] = make_int2(s, d);
  }
}

// K4: per-bucket CSR finalize. rowptr[n] = END of node n (start = rowptr[n-1]).
__global__ __launch_bounds__(256) void csr_bucket(const int2* __restrict__ eb,
    const int* __restrict__ bh, int E, int N,
    int* __restrict__ rowptr, int* __restrict__ csr) {
  __shared__ int deg[512];
  __shared__ int sm[256];
  const int t = threadIdx.x;
  const int bucket = blockIdx.x;
  const int bstart = bh[bucket * NBLKB];
  const int bend = (bucket + 1 < NBUCK) ? bh[(bucket + 1) * NBLKB] : E;
  const int n0 = bucket << 9;
  deg[t] = 0; deg[t + 256] = 0;
  __syncthreads();
  for (int j = bstart + t; j < bend; j += 256) atomicAdd(&deg[eb[j].y - n0], 1);
  __syncthreads();
  const int v0 = deg[2 * t], v1 = deg[2 * t + 1];
  const int s = v0 + v1;
  sm[t] = s;
  __syncthreads();
  for (int o = 1; o < 256; o <<= 1) {
    const int x = (t >= o) ? sm[t - o] : 0;
    __syncthreads();
    sm[t] += x;
    __syncthreads();
  }
  const int base = sm[t] - s;          // exclusive prefix over 2t
  if (n0 + 2 * t < N)     rowptr[n0 + 2 * t]     = bstart + base + v0;
  if (n0 + 2 * t + 1 < N) rowptr[n0 + 2 * t + 1] = bstart + base + v0 + v1;
  deg[2 * t] = base;
  deg[2 * t + 1] = base + v0;
  __syncthreads();
  for (int j = bstart + t; j < bend; j += 256) {
    const int2 e = eb[j];
    const int pos = bstart + atomicAdd(&deg[e.y - n0], 1);
    csr[pos] = e.x;
  }
}

// ---------------- layer-1 gather (prefetched, f16 payload) ------------------
__global__ __launch_bounds__(256) void gather_h8(const __half* __restrict__ xl,
    const float* __restrict__ es, const float* __restrict__ ed,
    const int* __restrict__ rowptr, const int* __restrict__ csr,
    const float* __restrict__ bias, __half* __restrict__ hout, int N) {
  const int wave = threadIdx.x >> 6, lane = threadIdx.x & 63;
  const int n = blockIdx.x * 4 + wave;
  if (n >= N) return;
  const int h = lane >> 3;
  const float edv = ed[n * 8 + h];
  const int start = (n == 0) ? 0 : rowptr[n - 1];
  const int end = rowptr[n];

  float2 acc;
  float ssum;
  {
    const float ee = __expf(lrelu(es[n * 8 + h] + edv));
    const float2 xv = __half22float2(*(const __half2*)&xl[(size_t)n * 128 + lane * 2]);
    acc.x = ee * xv.x; acc.y = ee * xv.y; ssum = ee;
  }
  constexpr int P = 8;
  int j = start;
  for (; j + P <= end; j += P) {
    int srcs[P];
#pragma unroll
    for (int k = 0; k < P; ++k) srcs[k] = csr[j + k];
    float ev[P];
    __half2 xv[P];
#pragma unroll
    for (int k = 0; k < P; ++k) {
      ev[k] = es[srcs[k] * 8 + h];
      xv[k] = *(const __half2*)&xl[(size_t)srcs[k] * 128 + lane * 2];
    }
#pragma unroll
    for (int k = 0; k < P; ++k) {
      const float ee = __expf(lrelu(ev[k] + edv));
      const float2 f = __half22float2(xv[k]);
      acc.x += ee * f.x; acc.y += ee * f.y; ssum += ee;
    }
  }
  for (; j < end; ++j) {
    const int src = csr[j];
    const float ee = __expf(lrelu(es[src * 8 + h] + edv));
    const float2 f = __half22float2(*(const __half2*)&xl[(size_t)src * 128 + lane * 2]);
    acc.x += ee * f.x; acc.y += ee * f.y; ssum += ee;
  }
  const float inv = 1.f / (ssum + 1e-16f);
  const int c = lane * 2;
  float v0 = acc.x * inv + bias[c];
  float v1 = acc.y * inv + bias[c + 1];
  v0 = v0 > 0.f ? v0 : __expf(v0) - 1.f;
  v1 = v1 > 0.f ? v1 : __expf(v1) - 1.f;
  *(__half2*)&hout[(size_t)n * 128 + c] = __floats2half2_rn(v0, v1);
}

// ---------------- layer-2 gather (prefetched, f16 payload), plain store -----
__global__ __launch_bounds__(256) void gather_h1(const __half* __restrict__ xl2,
    const float* __restrict__ es, const float* __restrict__ ed,
    const int* __restrict__ rowptr, const int* __restrict__ csr,
    const float* __restrict__ bias, float* __restrict__ vout, int N) {
  const int wave = threadIdx.x >> 6, lane = threadIdx.x & 63;
  const int n = blockIdx.x * 4 + wave;
  if (n >= N) return;
  const float edv = ed[n];
  const int start = (n == 0) ? 0 : rowptr[n - 1];
  const int end = rowptr[n];

  float ee0 = __expf(lrelu(es[n] + edv));
  float acc = ee0 * __half2float(xl2[(size_t)n * 64 + lane]);
  float ssum = ee0;
  constexpr int P = 8;
  int j = start;
  for (; j + P <= end; j += P) {
    int srcs[P];
#pragma unroll
    for (int k = 0; k < P; ++k) srcs[k] = csr[j + k];
    float ev[P];
    __half xv[P];
#pragma unroll
    for (int k = 0; k < P; ++k) {
      ev[k] = es[srcs[k]];
      xv[k] = xl2[(size_t)srcs[k] * 64 + lane];
    }
#pragma unroll
    for (int k = 0; k < P; ++k) {
      const float e2 = __expf(lrelu(ev[k] + edv));
      acc += e2 * __half2float(xv[k]); ssum += e2;
    }
  }
  for (; j < end; ++j) {
    const int src = csr[j];
    const float e2 = __expf(lrelu(es[src] + edv));
    acc += e2 * __half2float(xl2[(size_t)src * 64 + lane]);
    ssum += e2;
  }
  vout[(size_t)n * 64 + lane] = acc / (ssum + 1e-16f) + bias[lane];
}

// ---------------- segmented mean pool: 1 block per graph --------------------
__global__ __launch_bounds__(256) void pool_seg(const float* __restrict__ v,
    const int* __restrict__ batch, float* __restrict__ out, int N) {
  const int g = blockIdx.x;
  const int t = threadIdx.x;
  int lo = 0, hi = N;
  while (lo < hi) { const int m = (lo + hi) >> 1; if (batch[m] < g) lo = m + 1; else hi = m; }
  const int start = lo;
  hi = N;
  while (lo < hi) { const int m = (lo + hi) >> 1; if (batch[m] <= g) lo = m + 1; else hi = m; }
  const int end = lo;

  const int c = t & 63, rg = t >> 6;
  float s = 0.f;
  for (int r = start + rg; r < end; r += 4) s += v[(size_t)r * 64 + c];
  __shared__ float sm[256];
  sm[t] = s;
  __syncthreads();
  if (t < 64) {
    const float tot = sm[t] + sm[t + 64] + sm[t + 128] + sm[t + 192];
    out[g * 64 + t] = tot / fmaxf((float)(end - start), 1.f);
  }
}

extern "C" void kernel_launch(void* const* d_in, const int* in_sizes, int n_in,
                              void* d_out, int out_size, void* d_ws, size_t ws_size,
                              hipStream_t stream) {
  const float* x   = (const float*)d_in[0];
  const float* W1  = (const float*)d_in[1];
  const float* as1 = (const float*)d_in[2];
  const float* ad1 = (const float*)d_in[3];
  const float* b1  = (const float*)d_in[4];
  const float* W2  = (const float*)d_in[5];
  const float* as2 = (const float*)d_in[6];
  const float* ad2 = (const float*)d_in[7];
  const float* b2  = (const float*)d_in[8];
  const int* ei    = (const int*)d_in[9];
  const int* batch = (const int*)d_in[10];
  float* out = (float*)d_out;
  const int N = in_sizes[10];      // 100000
  const int E = in_sizes[9] / 2;   // 1600000
  const int G = out_size / 64;     // 256 graphs
  const int BH = NBUCK * NBLKB;    // 131072

  // workspace layout (bytes), with reuse:
  char* ws = (char*)d_ws;
  __half* xl  = (__half*)ws;                         // [N*128] f16
  __half* h   = (__half*)(ws + (size_t)N * 256);     // [N*128] f16
  __half* xl2 = xl;                                  // [N*64] f16 (xl dead)
  float* vbuf = (float*)(ws + (size_t)N * 256);      // [N*64] f32 (h dead)
  float* es1  = (float*)(ws + (size_t)N * 512);      // [N*8]
  float* ed1  = es1 + (size_t)N * 8;                 // [N*8]
  float* es2  = es1;                                 // [N]
  float* ed2  = es1 + N;                             // [N]
  int* rowptr = (int*)(ed1 + (size_t)N * 8);         // [N]
  int* csr    = rowptr + N;                          // [E]
  int2* eb    = (int2*)((((uintptr_t)(csr + E)) + 7) & ~(uintptr_t)7); // [E]
  int* bh     = (int*)(eb + E);                      // [131072]
  int* ctot   = bh + BH;                             // [128]

  // ---- CSR build: LDS counting sort (no global atomics) ----
  bucket_hist<<<NBLKB, 256, 0, stream>>>(ei, E, bh);
  scanA<<<BH / 1024, 256, 0, stream>>>(bh, ctot, BH);
  scanB<<<1, 128, 0, stream>>>(ctot, BH / 1024);
  scanC<<<BH / 256, 256, 0, stream>>>(bh, ctot, BH);
  bucket_scatter<<<NBLKB, 256, 0, stream>>>(ei, E, bh, eb);
  csr_bucket<<<(N + 511) / 512, 256, 0, stream>>>(eb, bh, E, N, rowptr, csr);

  // ---- layer 1 ----
  gemm_rm<float, 128, 32, 64><<<(N + 31) / 32, 256, 0, stream>>>(x, W1, xl, N);
  att_h8<<<(N + 1) / 2, 256, 0, stream>>>(xl, as1, ad1, es1, ed1, N);
  gather_h8<<<(N + 3) / 4, 256, 0, stream>>>(xl, es1, ed1, rowptr, csr, b1, h, N);

  // ---- layer 2 ----
  gemm_rm<__half, 64, 64, 128><<<(N + 63) / 64, 256, 0, stream>>>(h, W2, xl2, N);
  att_h1<<<(N + 3) / 4, 256, 0, stream>>>(xl2, as2, ad2, es2, ed2, N);
  gather_h1<<<(N + 3) / 4, 256, 0, stream>>>(xl2, es2, ed2, rowptr, csr, b2, vbuf, N);

  // ---- global mean pool (segmented, no atomics) ----
  pool_seg<<<G, 256, 0, stream>>>(vbuf, batch, out, N);
}

// Round 7
// 321.226 us; speedup vs baseline: 5.8015x; 1.1546x over previous
//
#include <hip/hip_runtime.h>
#include <hip/hip_fp16.h>

// GAT 2-layer forward, MI355X. N=100000, E=1.6M (+N self-loops), Fin=128,
// H=8, C=16 (H*C=128), Fout=64, 256 graphs.
//
// Round 7: (a) multi-edge-per-wave gathers (2 edges x 32 lanes / 4 edges x
// 16 lanes) to cut per-edge VALU ~45%; (b) f16 MFMA GEMMs (16x16x32) with
// W pre-transposed to f16, B-frags read from L2-resident Wt.

#define LRELU_SLOPE 0.2f
#define NBLKB 512          // bucketing blocks
#define NBUCK 256          // buckets (dst>>9, N<=131072)

__device__ __forceinline__ float lrelu(float x) { return x > 0.f ? x : LRELU_SLOPE * x; }

typedef _Float16 f16x8 __attribute__((ext_vector_type(8)));
typedef float f32x4 __attribute__((ext_vector_type(4)));

// ---------------- W convert + transpose: Wt[m][k] = (f16)W[k][m] ------------
__global__ __launch_bounds__(256) void convWT(const float* __restrict__ W,
    __half* __restrict__ Wt, int K, int M) {
  const int i = blockIdx.x * 256 + threadIdx.x;
  if (i < K * M) {
    const int k = i / M, m = i % M;
    Wt[m * K + k] = __float2half(W[i]);
  }
}

// ---------------- MFMA GEMM: Y[N][M_](f16) = X[N][128] @ Wt^T ---------------
// A-frag: lane holds A[row=l&15][k=(l>>4)*8+j]; B-frag: B[k][col=l&15];
// D: D[row=(l>>4)*4+j][col=l&15]  (verified m89 mapping).
template<typename TX, int M_>
__global__ __launch_bounds__(256) void gemm_mfma(const TX* __restrict__ X,
    const __half* __restrict__ Wt, __half* __restrict__ Y, int N) {
  constexpr int K = 128;
  constexpr int BM = 64;
  constexpr int LP = K + 8;                 // LDS pitch in halves (272B rows)
  __shared__ _Float16 Xl[BM * LP];
  const int tid = threadIdx.x;
  const int row0 = blockIdx.x * BM;

  if constexpr (sizeof(TX) == 4) {          // f32 input -> convert
    for (int i = tid; i < BM * (K / 4); i += 256) {
      const int r = i / (K / 4), c4 = (i % (K / 4)) * 4;
      int gr = row0 + r; if (gr >= N) gr = N - 1;
      const float4 v = *(const float4*)((const float*)X + (size_t)gr * K + c4);
      _Float16* d = &Xl[r * LP + c4];
      d[0] = (_Float16)v.x; d[1] = (_Float16)v.y;
      d[2] = (_Float16)v.z; d[3] = (_Float16)v.w;
    }
  } else {                                  // f16 input
    for (int i = tid; i < BM * (K / 8); i += 256) {
      const int r = i / (K / 8), c8 = (i % (K / 8)) * 8;
      int gr = row0 + r; if (gr >= N) gr = N - 1;
      const f16x8 v = *(const f16x8*)((const _Float16*)X + (size_t)gr * K + c8);
      *(f16x8*)&Xl[r * LP + c8] = v;
    }
  }
  __syncthreads();

  const int w = tid >> 6, l = tid & 63;
  const int lrow = l & 15, lk = (l >> 4) * 8;
  constexpr int NT = M_ / 16;
  f32x4 acc[NT];
#pragma unroll
  for (int n = 0; n < NT; ++n) acc[n] = (f32x4){0.f, 0.f, 0.f, 0.f};

#pragma unroll
  for (int kk = 0; kk < K; kk += 32) {
    const f16x8 a = *(const f16x8*)&Xl[(w * 16 + lrow) * LP + kk + lk];
#pragma unroll
    for (int n = 0; n < NT; ++n) {
      const f16x8 b = *(const f16x8*)((const _Float16*)Wt +
                        (size_t)(n * 16 + lrow) * K + kk + lk);
      acc[n] = __builtin_amdgcn_mfma_f32_16x16x32_f16(a, b, acc[n], 0, 0, 0);
    }
  }
  const int orow = row0 + w * 16 + (l >> 4) * 4;
#pragma unroll
  for (int n = 0; n < NT; ++n) {
#pragma unroll
    for (int j = 0; j < 4; ++j) {
      const int gr = orow + j;
      if (gr < N) Y[(size_t)gr * M_ + n * 16 + lrow] = __float2half(acc[n][j]);
    }
  }
}

// ---------------- attention scalars (f16 input) -----------------------------
__global__ __launch_bounds__(256) void att_h8(const __half* __restrict__ xl,
    const float* __restrict__ as, const float* __restrict__ ad,
    float* __restrict__ es, float* __restrict__ ed, int N) {
  const int n = blockIdx.x * 2 + (threadIdx.x >> 7);
  const int c = threadIdx.x & 127;
  if (n >= N) return;
  const float v = __half2float(xl[(size_t)n * 128 + c]);
  float ps = v * as[c];
  float pd = v * ad[c];
#pragma unroll
  for (int o = 8; o >= 1; o >>= 1) {
    ps += __shfl_xor(ps, o, 16);
    pd += __shfl_xor(pd, o, 16);
  }
  if ((c & 15) == 0) {
    es[n * 8 + (c >> 4)] = ps;
    ed[n * 8 + (c >> 4)] = pd;
  }
}

__global__ __launch_bounds__(256) void att_h1(const __half* __restrict__ xl2,
    const float* __restrict__ as, const float* __restrict__ ad,
    float* __restrict__ es, float* __restrict__ ed, int N) {
  const int n = blockIdx.x * 4 + (threadIdx.x >> 6);
  const int c = threadIdx.x & 63;
  if (n >= N) return;
  const float v = __half2float(xl2[(size_t)n * 64 + c]);
  float ps = v * as[c];
  float pd = v * ad[c];
#pragma unroll
  for (int o = 32; o >= 1; o >>= 1) {
    ps += __shfl_xor(ps, o, 64);
    pd += __shfl_xor(pd, o, 64);
  }
  if (c == 0) { es[n] = ps; ed[n] = pd; }
}

// ---------------- CSR build: LDS counting sort ------------------------------
__global__ __launch_bounds__(256) void bucket_hist(const int* __restrict__ ei, int E,
    int* __restrict__ bh) {
  __shared__ int hist[NBUCK];
  const int t = threadIdx.x;
  hist[t] = 0;
  __syncthreads();
  const int chunk = (E + NBLKB - 1) / NBLKB;
  const int s0 = blockIdx.x * chunk;
  const int s1 = min(E, s0 + chunk);
  for (int e = s0 + t; e < s1; e += 256) atomicAdd(&hist[ei[E + e] >> 9], 1);
  __syncthreads();
  bh[t * NBLKB + blockIdx.x] = hist[t];
}

__global__ __launch_bounds__(256) void scanA(int* __restrict__ a, int* __restrict__ ctot, int N) {
  __shared__ int sm[256];
  const int base = blockIdx.x * 1024;
  const int t = threadIdx.x;
  int v[4], s = 0;
#pragma unroll
  for (int i = 0; i < 4; ++i) {
    const int idx = base + t * 4 + i;
    v[i] = (idx < N) ? a[idx] : 0;
    s += v[i];
  }
  sm[t] = s;
  __syncthreads();
  for (int o = 1; o < 256; o <<= 1) {
    const int x = (t >= o) ? sm[t - o] : 0;
    __syncthreads();
    sm[t] += x;
    __syncthreads();
  }
  if (t == 255) ctot[blockIdx.x] = sm[255];
  int run = sm[t] - s;
#pragma unroll
  for (int i = 0; i < 4; ++i) {
    const int idx = base + t * 4 + i;
    if (idx < N) a[idx] = run;
    run += v[i];
  }
}

__global__ __launch_bounds__(128) void scanB(int* __restrict__ ctot, int n) {
  __shared__ int sm[128];
  const int t = threadIdx.x;
  const int v = (t < n) ? ctot[t] : 0;
  sm[t] = v;
  __syncthreads();
  for (int o = 1; o < 128; o <<= 1) {
    const int x = (t >= o) ? sm[t - o] : 0;
    __syncthreads();
    sm[t] += x;
    __syncthreads();
  }
  if (t < n) ctot[t] = sm[t] - v;
}

__global__ __launch_bounds__(256) void scanC(int* __restrict__ a, const int* __restrict__ ctot, int N) {
  const int i = blockIdx.x * 256 + threadIdx.x;
  if (i < N) a[i] += ctot[i >> 10];
}

__global__ __launch_bounds__(256) void bucket_scatter(const int* __restrict__ ei, int E,
    const int* __restrict__ bh, int2* __restrict__ eb) {
  __shared__ int offs[NBUCK];
  const int t = threadIdx.x;
  offs[t] = bh[t * NBLKB + blockIdx.x];
  __syncthreads();
  const int chunk = (E + NBLKB - 1) / NBLKB;
  const int s0 = blockIdx.x * chunk;
  const int s1 = min(E, s0 + chunk);
  for (int e = s0 + t; e < s1; e += 256) {
    const int s = ei[e], d = ei[E + e];
    const int pos = atomicAdd(&offs[d >> 9], 1);
    eb[pos] = make_int2(s, d);
  }
}

__global__ __launch_bounds__(256) void csr_bucket(const int2* __restrict__ eb,
    const int* __restrict__ bh, int E, int N,
    int* __restrict__ rowptr, int* __restrict__ csr) {
  __shared__ int deg[512];
  __shared__ int sm[256];
  const int t = threadIdx.x;
  const int bucket = blockIdx.x;
  const int bstart = bh[bucket * NBLKB];
  const int bend = (bucket + 1 < NBUCK) ? bh[(bucket + 1) * NBLKB] : E;
  const int n0 = bucket << 9;
  deg[t] = 0; deg[t + 256] = 0;
  __syncthreads();
  for (int j = bstart + t; j < bend; j += 256) atomicAdd(&deg[eb[j].y - n0], 1);
  __syncthreads();
  const int v0 = deg[2 * t], v1 = deg[2 * t + 1];
  const int s = v0 + v1;
  sm[t] = s;
  __syncthreads();
  for (int o = 1; o < 256; o <<= 1) {
    const int x = (t >= o) ? sm[t - o] : 0;
    __syncthreads();
    sm[t] += x;
    __syncthreads();
  }
  const int base = sm[t] - s;
  if (n0 + 2 * t < N)     rowptr[n0 + 2 * t]     = bstart + base + v0;
  if (n0 + 2 * t + 1 < N) rowptr[n0 + 2 * t + 1] = bstart + base + v0 + v1;
  deg[2 * t] = base;
  deg[2 * t + 1] = base + v0;
  __syncthreads();
  for (int j = bstart + t; j < bend; j += 256) {
    const int2 e = eb[j];
    const int pos = bstart + atomicAdd(&deg[e.y - n0], 1);
    csr[pos] = e.x;
  }
}

// ---------------- layer-1 gather: 2 edges/wave, 32 lanes x 4ch each ---------
__global__ __launch_bounds__(256) void gather_h8(const __half* __restrict__ xl,
    const float* __restrict__ es, const float* __restrict__ ed,
    const int* __restrict__ rowptr, const int* __restrict__ csr,
    const float* __restrict__ bias, __half* __restrict__ hout, int N) {
  const int wave = threadIdx.x >> 6, lane = threadIdx.x & 63;
  const int n = blockIdx.x * 4 + wave;
  if (n >= N) return;
  const int sub = lane >> 5;       // which edge of the pair
  const int sl  = lane & 31;       // channels 4sl..4sl+3
  const int c0  = sl * 4;
  const int h   = sl >> 2;
  const float edv = ed[n * 8 + h];
  const int start = (n == 0) ? 0 : rowptr[n - 1];
  const int end   = rowptr[n];
  union U8 { uint2 u; __half2 h2[2]; };

  float4 acc = make_float4(0.f, 0.f, 0.f, 0.f);
  float ssum = 0.f;
  if (sub == 0) {    // self loop
    const float ee = __expf(lrelu(es[n * 8 + h] + edv));
    U8 r; r.u = *(const uint2*)&xl[(size_t)n * 128 + c0];
    const float2 f0 = __half22float2(r.h2[0]), f1 = __half22float2(r.h2[1]);
    acc.x = ee * f0.x; acc.y = ee * f0.y; acc.z = ee * f1.x; acc.w = ee * f1.y;
    ssum = ee;
  }
  int j = start + sub;
  for (; j + 6 < end; j += 8) {    // 4 edges per sub per trip (8/wave)
    int s0 = csr[j], s1 = csr[j + 2], s2 = csr[j + 4], s3 = csr[j + 6];
    float ev[4]; U8 r[4];
    ev[0] = es[s0 * 8 + h]; r[0].u = *(const uint2*)&xl[(size_t)s0 * 128 + c0];
    ev[1] = es[s1 * 8 + h]; r[1].u = *(const uint2*)&xl[(size_t)s1 * 128 + c0];
    ev[2] = es[s2 * 8 + h]; r[2].u = *(const uint2*)&xl[(size_t)s2 * 128 + c0];
    ev[3] = es[s3 * 8 + h]; r[3].u = *(const uint2*)&xl[(size_t)s3 * 128 + c0];
#pragma unroll
    for (int k = 0; k < 4; ++k) {
      const float ee = __expf(lrelu(ev[k] + edv));
      const float2 f0 = __half22float2(r[k].h2[0]), f1 = __half22float2(r[k].h2[1]);
      acc.x += ee * f0.x; acc.y += ee * f0.y;
      acc.z += ee * f1.x; acc.w += ee * f1.y;
      ssum += ee;
    }
  }
  for (; j < end; j += 2) {
    const int src = csr[j];
    const float ee = __expf(lrelu(es[src * 8 + h] + edv));
    U8 r; r.u = *(const uint2*)&xl[(size_t)src * 128 + c0];
    const float2 f0 = __half22float2(r.h2[0]), f1 = __half22float2(r.h2[1]);
    acc.x += ee * f0.x; acc.y += ee * f0.y;
    acc.z += ee * f1.x; acc.w += ee * f1.y;
    ssum += ee;
  }
  acc.x += __shfl_xor(acc.x, 32); acc.y += __shfl_xor(acc.y, 32);
  acc.z += __shfl_xor(acc.z, 32); acc.w += __shfl_xor(acc.w, 32);
  ssum  += __shfl_xor(ssum, 32);
  if (sub == 0) {
    const float inv = 1.f / (ssum + 1e-16f);
    const float4 b4 = *(const float4*)&bias[c0];
    float v0 = acc.x * inv + b4.x, v1 = acc.y * inv + b4.y;
    float v2 = acc.z * inv + b4.z, v3 = acc.w * inv + b4.w;
    v0 = v0 > 0.f ? v0 : __expf(v0) - 1.f;
    v1 = v1 > 0.f ? v1 : __expf(v1) - 1.f;
    v2 = v2 > 0.f ? v2 : __expf(v2) - 1.f;
    v3 = v3 > 0.f ? v3 : __expf(v3) - 1.f;
    U8 o; o.h2[0] = __floats2half2_rn(v0, v1); o.h2[1] = __floats2half2_rn(v2, v3);
    *(uint2*)&hout[(size_t)n * 128 + c0] = o.u;
  }
}

// ---------------- layer-2 gather: 4 edges/wave, 16 lanes x 4ch each ---------
__global__ __launch_bounds__(256) void gather_h1(const __half* __restrict__ xl2,
    const float* __restrict__ es, const float* __restrict__ ed,
    const int* __restrict__ rowptr, const int* __restrict__ csr,
    const float* __restrict__ bias, float* __restrict__ vout, int N) {
  const int wave = threadIdx.x >> 6, lane = threadIdx.x & 63;
  const int n = blockIdx.x * 4 + wave;
  if (n >= N) return;
  const int sub = lane >> 4;       // 0..3
  const int sl  = lane & 15;       // channels 4sl..4sl+3
  const int c0  = sl * 4;
  const float edv = ed[n];
  const int start = (n == 0) ? 0 : rowptr[n - 1];
  const int end   = rowptr[n];
  union U8 { uint2 u; __half2 h2[2]; };

  float4 acc = make_float4(0.f, 0.f, 0.f, 0.f);
  float ssum = 0.f;
  if (sub == 0) {    // self loop
    const float ee = __expf(lrelu(es[n] + edv));
    U8 r; r.u = *(const uint2*)&xl2[(size_t)n * 64 + c0];
    const float2 f0 = __half22float2(r.h2[0]), f1 = __half22float2(r.h2[1]);
    acc.x = ee * f0.x; acc.y = ee * f0.y; acc.z = ee * f1.x; acc.w = ee * f1.y;
    ssum = ee;
  }
  int j = start + sub;
  for (; j + 4 < end; j += 8) {    // 2 edges per sub per trip (8/wave)
    const int s0 = csr[j], s1 = csr[j + 4];
    const float e0 = es[s0], e1 = es[s1];
    U8 r0, r1;
    r0.u = *(const uint2*)&xl2[(size_t)s0 * 64 + c0];
    r1.u = *(const uint2*)&xl2[(size_t)s1 * 64 + c0];
    {
      const float ee = __expf(lrelu(e0 + edv));
      const float2 f0 = __half22float2(r0.h2[0]), f1 = __half22float2(r0.h2[1]);
      acc.x += ee * f0.x; acc.y += ee * f0.y;
      acc.z += ee * f1.x; acc.w += ee * f1.y; ssum += ee;
    }
    {
      const float ee = __expf(lrelu(e1 + edv));
      const float2 f0 = __half22float2(r1.h2[0]), f1 = __half22float2(r1.h2[1]);
      acc.x += ee * f0.x; acc.y += ee * f0.y;
      acc.z += ee * f1.x; acc.w += ee * f1.y; ssum += ee;
    }
  }
  for (; j < end; j += 4) {
    const int src = csr[j];
    const float ee = __expf(lrelu(es[src] + edv));
    U8 r; r.u = *(const uint2*)&xl2[(size_t)src * 64 + c0];
    const float2 f0 = __half22float2(r.h2[0]), f1 = __half22float2(r.h2[1]);
    acc.x += ee * f0.x; acc.y += ee * f0.y;
    acc.z += ee * f1.x; acc.w += ee * f1.y; ssum += ee;
  }
#pragma unroll
  for (int o = 16; o <= 32; o <<= 1) {
    acc.x += __shfl_xor(acc.x, o); acc.y += __shfl_xor(acc.y, o);
    acc.z += __shfl_xor(acc.z, o); acc.w += __shfl_xor(acc.w, o);
    ssum  += __shfl_xor(ssum, o);
  }
  if (sub == 0) {
    const float inv = 1.f / (ssum + 1e-16f);
    const float4 b4 = *(const float4*)&bias[c0];
    float4 o;
    o.x = acc.x * inv + b4.x; o.y = acc.y * inv + b4.y;
    o.z = acc.z * inv + b4.z; o.w = acc.w * inv + b4.w;
    *(float4*)&vout[(size_t)n * 64 + c0] = o;
  }
}

// ---------------- segmented mean pool: 1 block per graph --------------------
__global__ __launch_bounds__(256) void pool_seg(const float* __restrict__ v,
    const int* __restrict__ batch, float* __restrict__ out, int N) {
  const int g = blockIdx.x;
  const int t = threadIdx.x;
  int lo = 0, hi = N;
  while (lo < hi) { const int m = (lo + hi) >> 1; if (batch[m] < g) lo = m + 1; else hi = m; }
  const int start = lo;
  hi = N;
  while (lo < hi) { const int m = (lo + hi) >> 1; if (batch[m] <= g) lo = m + 1; else hi = m; }
  const int end = lo;

  const int c = t & 63, rg = t >> 6;
  float s = 0.f;
  for (int r = start + rg; r < end; r += 4) s += v[(size_t)r * 64 + c];
  __shared__ float sm[256];
  sm[t] = s;
  __syncthreads();
  if (t < 64) {
    const float tot = sm[t] + sm[t + 64] + sm[t + 128] + sm[t + 192];
    out[g * 64 + t] = tot / fmaxf((float)(end - start), 1.f);
  }
}

extern "C" void kernel_launch(void* const* d_in, const int* in_sizes, int n_in,
                              void* d_out, int out_size, void* d_ws, size_t ws_size,
                              hipStream_t stream) {
  const float* x   = (const float*)d_in[0];
  const float* W1  = (const float*)d_in[1];
  const float* as1 = (const float*)d_in[2];
  const float* ad1 = (const float*)d_in[3];
  const float* b1  = (const float*)d_in[4];
  const float* W2  = (const float*)d_in[5];
  const float* as2 = (const float*)d_in[6];
  const float* ad2 = (const float*)d_in[7];
  const float* b2  = (const float*)d_in[8];
  const int* ei    = (const int*)d_in[9];
  const int* batch = (const int*)d_in[10];
  float* out = (float*)d_out;
  const int N = in_sizes[10];      // 100000
  const int E = in_sizes[9] / 2;   // 1600000
  const int G = out_size / 64;     // 256 graphs
  const int BH = NBUCK * NBLKB;    // 131072

  // workspace layout (bytes), with reuse:
  char* ws = (char*)d_ws;
  __half* xl  = (__half*)ws;                         // [N*128] f16
  __half* h   = (__half*)(ws + (size_t)N * 256);     // [N*128] f16
  __half* xl2 = xl;                                  // [N*64] f16 (xl dead)
  float* vbuf = (float*)(ws + (size_t)N * 256);      // [N*64] f32 (h dead)
  float* es1  = (float*)(ws + (size_t)N * 512);      // [N*8]
  float* ed1  = es1 + (size_t)N * 8;                 // [N*8]
  float* es2  = es1;                                 // [N]
  float* ed2  = es1 + N;                             // [N]
  int* rowptr = (int*)(ed1 + (size_t)N * 8);         // [N]
  int* csr    = rowptr + N;                          // [E]
  int2* eb    = (int2*)((((uintptr_t)(csr + E)) + 7) & ~(uintptr_t)7); // [E]
  int* bh     = (int*)(eb + E);                      // [131072]
  int* ctot   = bh + BH;                             // [128]
  __half* Wt1 = (__half*)((((uintptr_t)(ctot + 128)) + 31) & ~(uintptr_t)31); // [128*128]
  __half* Wt2 = Wt1 + 128 * 128;                     // [64*128]

  // ---- W pre-convert (f16, transposed) ----
  convWT<<<(128 * 128 + 255) / 256, 256, 0, stream>>>(W1, Wt1, 128, 128);
  convWT<<<(128 * 64 + 255) / 256, 256, 0, stream>>>(W2, Wt2, 128, 64);

  // ---- CSR build: LDS counting sort (no global atomics) ----
  bucket_hist<<<NBLKB, 256, 0, stream>>>(ei, E, bh);
  scanA<<<BH / 1024, 256, 0, stream>>>(bh, ctot, BH);
  scanB<<<1, 128, 0, stream>>>(ctot, BH / 1024);
  scanC<<<BH / 256, 256, 0, stream>>>(bh, ctot, BH);
  bucket_scatter<<<NBLKB, 256, 0, stream>>>(ei, E, bh, eb);
  csr_bucket<<<(N + 511) / 512, 256, 0, stream>>>(eb, bh, E, N, rowptr, csr);

  // ---- layer 1 ----
  gemm_mfma<float, 128><<<(N + 63) / 64, 256, 0, stream>>>(x, Wt1, xl, N);
  att_h8<<<(N + 1) / 2, 256, 0, stream>>>(xl, as1, ad1, es1, ed1, N);
  gather_h8<<<(N + 3) / 4, 256, 0, stream>>>(xl, es1, ed1, rowptr, csr, b1, h, N);

  // ---- layer 2 ----
  gemm_mfma<__half, 64><<<(N + 63) / 64, 256, 0, stream>>>(h, Wt2, xl2, N);
  att_h1<<<(N + 3) / 4, 256, 0, stream>>>(xl2, as2, ad2, es2, ed2, N);
  gather_h1<<<(N + 3) / 4, 256, 0, stream>>>(xl2, es2, ed2, rowptr, csr, b2, vbuf, N);

  // ---- global mean pool (segmented, no atomics) ----
  pool_seg<<<G, 256, 0, stream>>>(vbuf, batch, out, N);
}

// Round 9
// 286.947 us; speedup vs baseline: 6.4945x; 1.1195x over previous
//
#include <hip/hip_runtime.h>
#include <hip/hip_fp16.h>

// GAT 2-layer forward, MI355X. N=100000, E=1.6M (+N self-loops), Fin=128,
// H=8, C=16 (H*C=128), Fout=64, 256 graphs.
//
// Round 9: r8 minus the LDS-elist flat-pointer trick (suspected crash: UB
// generic pointer `elist - bstart` underflowing the LDS aperture). Keeps:
// fused att epilogues, 1024-thr CSR hist/scatter + 512-thr finalize with
// packed (src<<9|dstlo) records, merged convWT.

#define LRELU_SLOPE 0.2f
#define NBLKB 512          // bucketing blocks
#define NBUCK 256          // buckets (dst>>9, N<=131072)

__device__ __forceinline__ float lrelu(float x) { return x > 0.f ? x : LRELU_SLOPE * x; }

typedef _Float16 f16x8 __attribute__((ext_vector_type(8)));
typedef float f32x4 __attribute__((ext_vector_type(4)));

// ---------------- W1+W2 convert + transpose (one launch) --------------------
__global__ __launch_bounds__(256) void convWT2(const float* __restrict__ W1,
    const float* __restrict__ W2, __half* __restrict__ Wt1, __half* __restrict__ Wt2) {
  const int i = blockIdx.x * 256 + threadIdx.x;
  if (i < 128 * 128) {
    const int k = i >> 7, m = i & 127;
    Wt1[m * 128 + k] = __float2half(W1[i]);
  } else {
    const int j = i - 128 * 128;
    if (j < 128 * 64) {
      const int k = j >> 6, m = j & 63;
      Wt2[m * 128 + k] = __float2half(W2[j]);
    }
  }
}

// ---------------- MFMA GEMM + fused attention scalars -----------------------
// A-frag: lane holds A[row=l&15][k=(l>>4)*8+j]; B-frag: B[k][col=l&15];
// D: D[row=(l>>4)*4+j][col=l&15]  (verified m89 mapping).
template<typename TX, int M_, int HEADS>
__global__ __launch_bounds__(256) void gemm_mfma(const TX* __restrict__ X,
    const __half* __restrict__ Wt, __half* __restrict__ Y,
    const float* __restrict__ as, const float* __restrict__ ad,
    float* __restrict__ es, float* __restrict__ ed, int N) {
  constexpr int K = 128;
  constexpr int BM = 64;
  constexpr int LP = K + 8;                 // LDS pitch in halves (272B rows)
  __shared__ _Float16 Xl[BM * LP];
  const int tid = threadIdx.x;
  const int row0 = blockIdx.x * BM;

  if constexpr (sizeof(TX) == 4) {          // f32 input -> convert
    for (int i = tid; i < BM * (K / 4); i += 256) {
      const int r = i / (K / 4), c4 = (i % (K / 4)) * 4;
      int gr = row0 + r; if (gr >= N) gr = N - 1;
      const float4 v = *(const float4*)((const float*)X + (size_t)gr * K + c4);
      _Float16* d = &Xl[r * LP + c4];
      d[0] = (_Float16)v.x; d[1] = (_Float16)v.y;
      d[2] = (_Float16)v.z; d[3] = (_Float16)v.w;
    }
  } else {                                  // f16 input
    for (int i = tid; i < BM * (K / 8); i += 256) {
      const int r = i / (K / 8), c8 = (i % (K / 8)) * 8;
      int gr = row0 + r; if (gr >= N) gr = N - 1;
      const f16x8 v = *(const f16x8*)((const _Float16*)X + (size_t)gr * K + c8);
      *(f16x8*)&Xl[r * LP + c8] = v;
    }
  }
  __syncthreads();

  const int w = tid >> 6, l = tid & 63;
  const int lrow = l & 15, lk = (l >> 4) * 8;
  constexpr int NT = M_ / 16;
  f32x4 acc[NT];
#pragma unroll
  for (int n = 0; n < NT; ++n) acc[n] = (f32x4){0.f, 0.f, 0.f, 0.f};

#pragma unroll
  for (int kk = 0; kk < K; kk += 32) {
    const f16x8 a = *(const f16x8*)&Xl[(w * 16 + lrow) * LP + kk + lk];
#pragma unroll
    for (int n = 0; n < NT; ++n) {
      const f16x8 b = *(const f16x8*)((const _Float16*)Wt +
                        (size_t)(n * 16 + lrow) * K + kk + lk);
      acc[n] = __builtin_amdgcn_mfma_f32_16x16x32_f16(a, b, acc[n], 0, 0, 0);
    }
  }
  const int orow = row0 + w * 16 + (l >> 4) * 4;
#pragma unroll
  for (int n = 0; n < NT; ++n) {
#pragma unroll
    for (int j = 0; j < 4; ++j) {
      const int gr = orow + j;
      if (gr < N) Y[(size_t)gr * M_ + n * 16 + lrow] = __float2half(acc[n][j]);
    }
  }

  // fused attention scalars
  if constexpr (HEADS == 8) {
#pragma unroll
    for (int n = 0; n < NT; ++n) {
#pragma unroll
      for (int j = 0; j < 4; ++j) {
        float ps = acc[n][j] * as[n * 16 + lrow];
        float pd = acc[n][j] * ad[n * 16 + lrow];
#pragma unroll
        for (int o = 1; o <= 8; o <<= 1) {
          ps += __shfl_xor(ps, o);
          pd += __shfl_xor(pd, o);
        }
        if (lrow == n) {
          const int gr = orow + j;
          if (gr < N) { es[gr * 8 + n] = ps; ed[gr * 8 + n] = pd; }
        }
      }
    }
  } else {
#pragma unroll
    for (int j = 0; j < 4; ++j) {
      float ps = 0.f, pd = 0.f;
#pragma unroll
      for (int n = 0; n < NT; ++n) {
        ps += acc[n][j] * as[n * 16 + lrow];
        pd += acc[n][j] * ad[n * 16 + lrow];
      }
#pragma unroll
      for (int o = 1; o <= 8; o <<= 1) {
        ps += __shfl_xor(ps, o);
        pd += __shfl_xor(pd, o);
      }
      if (lrow == 0) {
        const int gr = orow + j;
        if (gr < N) { es[gr] = ps; ed[gr] = pd; }
      }
    }
  }
}

// ---------------- CSR build: LDS counting sort (packed records) -------------
__global__ __launch_bounds__(1024) void bucket_hist(const int* __restrict__ ei, int E,
    int* __restrict__ bh) {
  __shared__ int hist[NBUCK];
  const int t = threadIdx.x;
  if (t < NBUCK) hist[t] = 0;
  __syncthreads();
  const int chunk = (E + NBLKB - 1) / NBLKB;
  const int s0 = blockIdx.x * chunk;
  const int s1 = min(E, s0 + chunk);
  for (int e = s0 + t; e < s1; e += 1024) atomicAdd(&hist[ei[E + e] >> 9], 1);
  __syncthreads();
  if (t < NBUCK) bh[t * NBLKB + blockIdx.x] = hist[t];
}

__global__ __launch_bounds__(256) void scanA(int* __restrict__ a, int* __restrict__ ctot, int N) {
  __shared__ int sm[256];
  const int base = blockIdx.x * 1024;
  const int t = threadIdx.x;
  int v[4], s = 0;
#pragma unroll
  for (int i = 0; i < 4; ++i) {
    const int idx = base + t * 4 + i;
    v[i] = (idx < N) ? a[idx] : 0;
    s += v[i];
  }
  sm[t] = s;
  __syncthreads();
  for (int o = 1; o < 256; o <<= 1) {
    const int x = (t >= o) ? sm[t - o] : 0;
    __syncthreads();
    sm[t] += x;
    __syncthreads();
  }
  if (t == 255) ctot[blockIdx.x] = sm[255];
  int run = sm[t] - s;
#pragma unroll
  for (int i = 0; i < 4; ++i) {
    const int idx = base + t * 4 + i;
    if (idx < N) a[idx] = run;
    run += v[i];
  }
}

__global__ __launch_bounds__(128) void scanB(int* __restrict__ ctot, int n) {
  __shared__ int sm[128];
  const int t = threadIdx.x;
  const int v = (t < n) ? ctot[t] : 0;
  sm[t] = v;
  __syncthreads();
  for (int o = 1; o < 128; o <<= 1) {
    const int x = (t >= o) ? sm[t - o] : 0;
    __syncthreads();
    sm[t] += x;
    __syncthreads();
  }
  if (t < n) ctot[t] = sm[t] - v;
}

__global__ __launch_bounds__(256) void scanC(int* __restrict__ a, const int* __restrict__ ctot, int N) {
  const int i = blockIdx.x * 256 + threadIdx.x;
  if (i < N) a[i] += ctot[i >> 10];
}

__global__ __launch_bounds__(1024) void bucket_scatter(const int* __restrict__ ei, int E,
    const int* __restrict__ bh, int* __restrict__ eb) {
  __shared__ int offs[NBUCK];
  const int t = threadIdx.x;
  if (t < NBUCK) offs[t] = bh[t * NBLKB + blockIdx.x];
  __syncthreads();
  const int chunk = (E + NBLKB - 1) / NBLKB;
  const int s0 = blockIdx.x * chunk;
  const int s1 = min(E, s0 + chunk);
  for (int e = s0 + t; e < s1; e += 1024) {
    const int s = ei[e], d = ei[E + e];
    const int pos = atomicAdd(&offs[d >> 9], 1);
    eb[pos] = (s << 9) | (d & 511);
  }
}

// per-bucket finalize: rowptr[n] = END of node n (start = rowptr[n-1])
__global__ __launch_bounds__(512) void csr_bucket(const int* __restrict__ eb,
    const int* __restrict__ bh, int E, int N,
    int* __restrict__ rowptr, int* __restrict__ csr) {
  __shared__ int deg[512];
  __shared__ int sm[512];
  const int t = threadIdx.x;
  const int bucket = blockIdx.x;
  const int bstart = bh[bucket * NBLKB];
  const int bend = (bucket + 1 < NBUCK) ? bh[(bucket + 1) * NBLKB] : E;
  const int n0 = bucket << 9;
  deg[t] = 0;
  __syncthreads();
  for (int j = bstart + t; j < bend; j += 512) atomicAdd(&deg[eb[j] & 511], 1);
  __syncthreads();
  const int v = deg[t];
  sm[t] = v;
  __syncthreads();
  for (int o = 1; o < 512; o <<= 1) {
    const int x = (t >= o) ? sm[t - o] : 0;
    __syncthreads();
    sm[t] += x;
    __syncthreads();
  }
  if (n0 + t < N) rowptr[n0 + t] = bstart + sm[t];
  deg[t] = bstart + sm[t] - v;          // start slot for scatter
  __syncthreads();
  for (int j = bstart + t; j < bend; j += 512) {
    const int e = eb[j];
    const int pos = atomicAdd(&deg[e & 511], 1);
    csr[pos] = e >> 9;
  }
}

// ---------------- layer-1 gather: 2 edges/wave, 32 lanes x 4ch each ---------
__global__ __launch_bounds__(256) void gather_h8(const __half* __restrict__ xl,
    const float* __restrict__ es, const float* __restrict__ ed,
    const int* __restrict__ rowptr, const int* __restrict__ csr,
    const float* __restrict__ bias, __half* __restrict__ hout, int N) {
  const int wave = threadIdx.x >> 6, lane = threadIdx.x & 63;
  const int n = blockIdx.x * 4 + wave;
  if (n >= N) return;
  const int sub = lane >> 5;       // which edge of the pair
  const int sl  = lane & 31;       // channels 4sl..4sl+3
  const int c0  = sl * 4;
  const int h   = sl >> 2;
  const float edv = ed[n * 8 + h];
  const int start = (n == 0) ? 0 : rowptr[n - 1];
  const int end   = rowptr[n];
  union U8 { uint2 u; __half2 h2[2]; };

  float4 acc = make_float4(0.f, 0.f, 0.f, 0.f);
  float ssum = 0.f;
  if (sub == 0) {    // self loop
    const float ee = __expf(lrelu(es[n * 8 + h] + edv));
    U8 r; r.u = *(const uint2*)&xl[(size_t)n * 128 + c0];
    const float2 f0 = __half22float2(r.h2[0]), f1 = __half22float2(r.h2[1]);
    acc.x = ee * f0.x; acc.y = ee * f0.y; acc.z = ee * f1.x; acc.w = ee * f1.y;
    ssum = ee;
  }
  int j = start + sub;
  for (; j + 6 < end; j += 8) {    // 4 edges per sub per trip (8/wave)
    int s0 = csr[j], s1 = csr[j + 2], s2 = csr[j + 4], s3 = csr[j + 6];
    float ev[4]; U8 r[4];
    ev[0] = es[s0 * 8 + h]; r[0].u = *(const uint2*)&xl[(size_t)s0 * 128 + c0];
    ev[1] = es[s1 * 8 + h]; r[1].u = *(const uint2*)&xl[(size_t)s1 * 128 + c0];
    ev[2] = es[s2 * 8 + h]; r[2].u = *(const uint2*)&xl[(size_t)s2 * 128 + c0];
    ev[3] = es[s3 * 8 + h]; r[3].u = *(const uint2*)&xl[(size_t)s3 * 128 + c0];
#pragma unroll
    for (int k = 0; k < 4; ++k) {
      const float ee = __expf(lrelu(ev[k] + edv));
      const float2 f0 = __half22float2(r[k].h2[0]), f1 = __half22float2(r[k].h2[1]);
      acc.x += ee * f0.x; acc.y += ee * f0.y;
      acc.z += ee * f1.x; acc.w += ee * f1.y;
      ssum += ee;
    }
  }
  for (; j < end; j += 2) {
    const int src = csr[j];
    const float ee = __expf(lrelu(es[src * 8 + h] + edv));
    U8 r; r.u = *(const uint2*)&xl[(size_t)src * 128 + c0];
    const float2 f0 = __half22float2(r.h2[0]), f1 = __half22float2(r.h2[1]);
    acc.x += ee * f0.x; acc.y += ee * f0.y;
    acc.z += ee * f1.x; acc.w += ee * f1.y;
    ssum += ee;
  }
  acc.x += __shfl_xor(acc.x, 32); acc.y += __shfl_xor(acc.y, 32);
  acc.z += __shfl_xor(acc.z, 32); acc.w += __shfl_xor(acc.w, 32);
  ssum  += __shfl_xor(ssum, 32);
  if (sub == 0) {
    const float inv = 1.f / (ssum + 1e-16f);
    const float4 b4 = *(const float4*)&bias[c0];
    float v0 = acc.x * inv + b4.x, v1 = acc.y * inv + b4.y;
    float v2 = acc.z * inv + b4.z, v3 = acc.w * inv + b4.w;
    v0 = v0 > 0.f ? v0 : __expf(v0) - 1.f;
    v1 = v1 > 0.f ? v1 : __expf(v1) - 1.f;
    v2 = v2 > 0.f ? v2 : __expf(v2) - 1.f;
    v3 = v3 > 0.f ? v3 : __expf(v3) - 1.f;
    U8 o; o.h2[0] = __floats2half2_rn(v0, v1); o.h2[1] = __floats2half2_rn(v2, v3);
    *(uint2*)&hout[(size_t)n * 128 + c0] = o.u;
  }
}

// ---------------- layer-2 gather: 4 edges/wave, 16 lanes x 4ch each ---------
__global__ __launch_bounds__(256) void gather_h1(const __half* __restrict__ xl2,
    const float* __restrict__ es, const float* __restrict__ ed,
    const int* __restrict__ rowptr, const int* __restrict__ csr,
    const float* __restrict__ bias, float* __restrict__ vout, int N) {
  const int wave = threadIdx.x >> 6, lane = threadIdx.x & 63;
  const int n = blockIdx.x * 4 + wave;
  if (n >= N) return;
  const int sub = lane >> 4;       // 0..3
  const int sl  = lane & 15;       // channels 4sl..4sl+3
  const int c0  = sl * 4;
  const float edv = ed[n];
  const int start = (n == 0) ? 0 : rowptr[n - 1];
  const int end   = rowptr[n];
  union U8 { uint2 u; __half2 h2[2]; };

  float4 acc = make_float4(0.f, 0.f, 0.f, 0.f);
  float ssum = 0.f;
  if (sub == 0) {    // self loop
    const float ee = __expf(lrelu(es[n] + edv));
    U8 r; r.u = *(const uint2*)&xl2[(size_t)n * 64 + c0];
    const float2 f0 = __half22float2(r.h2[0]), f1 = __half22float2(r.h2[1]);
    acc.x = ee * f0.x; acc.y = ee * f0.y; acc.z = ee * f1.x; acc.w = ee * f1.y;
    ssum = ee;
  }
  int j = start + sub;
  for (; j + 4 < end; j += 8) {    // 2 edges per sub per trip (8/wave)
    const int s0 = csr[j], s1 = csr[j + 4];
    const float e0 = es[s0], e1 = es[s1];
    U8 r0, r1;
    r0.u = *(const uint2*)&xl2[(size_t)s0 * 64 + c0];
    r1.u = *(const uint2*)&xl2[(size_t)s1 * 64 + c0];
    {
      const float ee = __expf(lrelu(e0 + edv));
      const float2 f0 = __half22float2(r0.h2[0]), f1 = __half22float2(r0.h2[1]);
      acc.x += ee * f0.x; acc.y += ee * f0.y;
      acc.z += ee * f1.x; acc.w += ee * f1.y; ssum += ee;
    }
    {
      const float ee = __expf(lrelu(e1 + edv));
      const float2 f0 = __half22float2(r1.h2[0]), f1 = __half22float2(r1.h2[1]);
      acc.x += ee * f0.x; acc.y += ee * f0.y;
      acc.z += ee * f1.x; acc.w += ee * f1.y; ssum += ee;
    }
  }
  for (; j < end; j += 4) {
    const int src = csr[j];
    const float ee = __expf(lrelu(es[src] + edv));
    U8 r; r.u = *(const uint2*)&xl2[(size_t)src * 64 + c0];
    const float2 f0 = __half22float2(r.h2[0]), f1 = __half22float2(r.h2[1]);
    acc.x += ee * f0.x; acc.y += ee * f0.y;
    acc.z += ee * f1.x; acc.w += ee * f1.y; ssum += ee;
  }
#pragma unroll
  for (int o = 16; o <= 32; o <<= 1) {
    acc.x += __shfl_xor(acc.x, o); acc.y += __shfl_xor(acc.y, o);
    acc.z += __shfl_xor(acc.z, o); acc.w += __shfl_xor(acc.w, o);
    ssum  += __shfl_xor(ssum, o);
  }
  if (sub == 0) {
    const float inv = 1.f / (ssum + 1e-16f);
    const float4 b4 = *(const float4*)&bias[c0];
    float4 o;
    o.x = acc.x * inv + b4.x; o.y = acc.y * inv + b4.y;
    o.z = acc.z * inv + b4.z; o.w = acc.w * inv + b4.w;
    *(float4*)&vout[(size_t)n * 64 + c0] = o;
  }
}

// ---------------- segmented mean pool: 1 block per graph --------------------
__global__ __launch_bounds__(256) void pool_seg(const float* __restrict__ v,
    const int* __restrict__ batch, float* __restrict__ out, int N) {
  const int g = blockIdx.x;
  const int t = threadIdx.x;
  int lo = 0, hi = N;
  while (lo < hi) { const int m = (lo + hi) >> 1; if (batch[m] < g) lo = m + 1; else hi = m; }
  const int start = lo;
  hi = N;
  while (lo < hi) { const int m = (lo + hi) >> 1; if (batch[m] <= g) lo = m + 1; else hi = m; }
  const int end = lo;

  const int c = t & 63, rg = t >> 6;
  float s = 0.f;
  for (int r = start + rg; r < end; r += 4) s += v[(size_t)r * 64 + c];
  __shared__ float sm[256];
  sm[t] = s;
  __syncthreads();
  if (t < 64) {
    const float tot = sm[t] + sm[t + 64] + sm[t + 128] + sm[t + 192];
    out[g * 64 + t] = tot / fmaxf((float)(end - start), 1.f);
  }
}

extern "C" void kernel_launch(void* const* d_in, const int* in_sizes, int n_in,
                              void* d_out, int out_size, void* d_ws, size_t ws_size,
                              hipStream_t stream) {
  const float* x   = (const float*)d_in[0];
  const float* W1  = (const float*)d_in[1];
  const float* as1 = (const float*)d_in[2];
  const float* ad1 = (const float*)d_in[3];
  const float* b1  = (const float*)d_in[4];
  const float* W2  = (const float*)d_in[5];
  const float* as2 = (const float*)d_in[6];
  const float* ad2 = (const float*)d_in[7];
  const float* b2  = (const float*)d_in[8];
  const int* ei    = (const int*)d_in[9];
  const int* batch = (const int*)d_in[10];
  float* out = (float*)d_out;
  const int N = in_sizes[10];      // 100000
  const int E = in_sizes[9] / 2;   // 1600000
  const int G = out_size / 64;     // 256 graphs
  const int BH = NBUCK * NBLKB;    // 131072

  // workspace layout (bytes), with reuse:
  char* ws = (char*)d_ws;
  __half* xl  = (__half*)ws;                         // [N*128] f16
  __half* h   = (__half*)(ws + (size_t)N * 256);     // [N*128] f16
  __half* xl2 = xl;                                  // [N*64] f16 (xl dead)
  float* vbuf = (float*)(ws + (size_t)N * 256);      // [N*64] f32 (h dead)
  float* es1  = (float*)(ws + (size_t)N * 512);      // [N*8]
  float* ed1  = es1 + (size_t)N * 8;                 // [N*8]
  float* es2  = es1;                                 // [N]
  float* ed2  = es1 + N;                             // [N]
  int* rowptr = (int*)(ed1 + (size_t)N * 8);         // [N]
  int* csr    = rowptr + N;                          // [E]
  int* eb     = csr + E;                             // [E] packed (src<<9|dstlo)
  int* bh     = eb + E;                              // [131072]
  int* ctot   = bh + BH;                             // [128]
  __half* Wt1 = (__half*)((((uintptr_t)(ctot + 128)) + 31) & ~(uintptr_t)31); // [128*128]
  __half* Wt2 = Wt1 + 128 * 128;                     // [64*128]

  // ---- W pre-convert (f16, transposed), one launch ----
  convWT2<<<(128 * 128 + 128 * 64 + 255) / 256, 256, 0, stream>>>(W1, W2, Wt1, Wt2);

  // ---- CSR build: LDS counting sort (no global atomics) ----
  bucket_hist<<<NBLKB, 1024, 0, stream>>>(ei, E, bh);
  scanA<<<BH / 1024, 256, 0, stream>>>(bh, ctot, BH);
  scanB<<<1, 128, 0, stream>>>(ctot, BH / 1024);
  scanC<<<BH / 256, 256, 0, stream>>>(bh, ctot, BH);
  bucket_scatter<<<NBLKB, 1024, 0, stream>>>(ei, E, bh, eb);
  csr_bucket<<<(N + 511) / 512, 512, 0, stream>>>(eb, bh, E, N, rowptr, csr);

  // ---- layer 1 (GEMM + fused att scalars) ----
  gemm_mfma<float, 128, 8><<<(N + 63) / 64, 256, 0, stream>>>(x, Wt1, xl, as1, ad1, es1, ed1, N);
  gather_h8<<<(N + 3) / 4, 256, 0, stream>>>(xl, es1, ed1, rowptr, csr, b1, h, N);

  // ---- layer 2 (GEMM + fused att scalars) ----
  gemm_mfma<__half, 64, 1><<<(N + 63) / 64, 256, 0, stream>>>(h, Wt2, xl2, as2, ad2, es2, ed2, N);
  gather_h1<<<(N + 3) / 4, 256, 0, stream>>>(xl2, es2, ed2, rowptr, csr, b2, vbuf, N);

  // ---- global mean pool (segmented, no atomics) ----
  pool_seg<<<G, 256, 0, stream>>>(vbuf, batch, out, N);
}